// Round 8
// baseline (479.934 us; speedup 1.0000x reference)
//
#include <hip/hip_runtime.h>
#include <hip/hip_fp16.h>
#include <math.h>

#define NN 8192
#define EE 131072
#define CC 64
#define GG 32
#define NEL 10
#define NBLK2 522

__device__ __forceinline__ float silu_f(float x) { return x / (1.0f + __expf(-x)); }

// stage a 64x64 row-major matrix W[c][d] into LDS transposed+XOR-swizzled
__device__ __forceinline__ void stage_wT(const float* __restrict__ W, float* sWT,
                                         int tid, int nt) {
    for (int idx = tid; idx < 4096; idx += nt) {
        int d = idx & 63, c = idx >> 6;
        sWT[(d << 6) + ((((c >> 2) ^ (d & 15)) << 2) | (c & 3))] = W[idx];
    }
}
#define WREAD(sWT, d, c4) (((const float4*)(sWT))[((d) << 4) + ((c4) ^ ((d) & 15))])
#define DOT4(a, b) ((a).x * (b).x + (a).y * (b).y + (a).z * (b).z + (a).w * (b).w)

// ---------------- h0 = W_embed[elem] ; elem = argmax ; element counts ---------------
__global__ __launch_bounds__(256) void k_h0(const float* __restrict__ na,
                                            const float* __restrict__ Wemb,
                                            float* __restrict__ h0,
                                            int* __restrict__ elem,
                                            int* __restrict__ cnt) {
    int n = blockIdx.x * 4 + (threadIdx.x >> 6);
    int d = threadIdx.x & 63;
    float acc = 0.0f;
    float best = -1.0f; int bi = 0;
    #pragma unroll
    for (int k = 0; k < NEL; k++) {
        float a = na[n * NEL + k];
        acc += a * Wemb[k * 64 + d];
        if (a > best) { best = a; bi = k; }
    }
    h0[n * 64 + d] = acc;
    if (d == 0) { elem[n] = bi; atomicAdd(&cnt[bi], 1); }
}

// ---------------- sc1 lookup table: sc1tab[e] = W_embed[e] @ Wsc1[e] ----------------
__global__ __launch_bounds__(64) void k_sc1tab(const float* __restrict__ Wemb,
                                               const float* __restrict__ Wsc1,
                                               float* __restrict__ tab) {
    int e = blockIdx.x, d = threadIdx.x;
    float acc = 0.0f;
    for (int c = 0; c < 64; c++)
        acc += Wemb[e * 64 + c] * Wsc1[e * 4096 + c * 64 + d];
    tab[e * 64 + d] = acc;
}

__global__ __launch_bounds__(256) void k_fill(const int* __restrict__ elem,
                                              int* cursor, int* __restrict__ order) {
    int n = blockIdx.x * 256 + threadIdx.x;
    int p = atomicAdd(&cursor[elem[n]], 1);
    order[p] = n;
}

// ---------------- CSR build over LIVE edges -----------------------------------------
__device__ __forceinline__ int edge_live(const float* pos, const float* shifts,
                                         const int* eidx, int e, int* rcv_out) {
    int snd = eidx[e];
    int rcv = eidx[EE + e];
    float vx = pos[rcv * 3 + 0] - pos[snd * 3 + 0] + shifts[e * 3 + 0];
    float vy = pos[rcv * 3 + 1] - pos[snd * 3 + 1] + shifts[e * 3 + 1];
    float vz = pos[rcv * 3 + 2] - pos[snd * 3 + 2] + shifts[e * 3 + 2];
    float r = sqrtf(vx * vx + vy * vy + vz * vz + 1e-12f);
    *rcv_out = rcv;
    return (r * 0.2f) < 1.0f;
}
__global__ __launch_bounds__(256) void k_csr_count(const float* __restrict__ pos,
                                                   const float* __restrict__ shifts,
                                                   const int* __restrict__ eidx,
                                                   int* __restrict__ rowcnt) {
    int e = blockIdx.x * 256 + threadIdx.x;
    int rcv;
    if (edge_live(pos, shifts, eidx, e, &rcv)) atomicAdd(&rowcnt[rcv], 1);
}
// scan rowcnt -> rowoff/rowcur ; element cnt -> offs/curs ; build node2 block map
__global__ __launch_bounds__(1024) void k_scan(const int* __restrict__ rowcnt,
                                               int* __restrict__ rowoff,
                                               int* __restrict__ rowcur,
                                               const int* __restrict__ cnt,
                                               int* __restrict__ offs,
                                               int* __restrict__ curs,
                                               int* __restrict__ belem,
                                               int* __restrict__ bbase,
                                               int* __restrict__ blim) {
    __shared__ int part[1024];
    int t = threadIdx.x;
    if (t < NBLK2) belem[t] = -1;
    int loc[8]; int s = 0;
    #pragma unroll
    for (int k = 0; k < 8; k++) { loc[k] = rowcnt[t * 8 + k]; s += loc[k]; }
    part[t] = s;
    __syncthreads();
    for (int d = 1; d < 1024; d <<= 1) {
        int v = (t >= d) ? part[t - d] : 0;
        __syncthreads();
        part[t] += v;
        __syncthreads();
    }
    int run = (t > 0) ? part[t - 1] : 0;
    #pragma unroll
    for (int k = 0; k < 8; k++) {
        rowoff[t * 8 + k] = run; rowcur[t * 8 + k] = run; run += loc[k];
    }
    if (t == 1023) rowoff[8192] = run;
    __syncthreads();
    if (t == 0) {
        int s2 = 0, b = 0;
        for (int e = 0; e < NEL; e++) {
            offs[e] = s2; curs[e] = s2;
            int c = cnt[e];
            for (int q = 0; q < c; q += 16) {
                belem[b] = e;
                bbase[b] = s2 + q;
                blim[b] = s2 + ((q + 16 < c) ? (q + 16) : c);
                b++;
            }
            s2 += c;
        }
    }
}
__global__ __launch_bounds__(256) void k_csr_fill(const float* __restrict__ pos,
                                                  const float* __restrict__ shifts,
                                                  const int* __restrict__ eidx,
                                                  int* __restrict__ rowcur,
                                                  int* __restrict__ elist) {
    int e = blockIdx.x * 256 + threadIdx.x;
    int rcv;
    if (edge_live(pos, shifts, eidx, e, &rcv)) {
        int p = atomicAdd(&rowcur[rcv], 1);
        elist[p] = e;
    }
}

// ---------------- edge MLP over CSR-ordered LIVE edges (unchanged) -------------------
__global__ __launch_bounds__(256) void edge_mlp(
    const float* __restrict__ feats, const float* __restrict__ pos,
    const float* __restrict__ shifts, const int* __restrict__ eidx,
    const int* __restrict__ elist, const int* __restrict__ rowoff,
    const float* __restrict__ Wra, const float* __restrict__ Wrb,
    unsigned int* __restrict__ msg, float4* __restrict__ ue4)
{
    int nlive = rowoff[NN];
    int e_base = blockIdx.x * 64;
    if (e_base >= nlive) return;

    __shared__ float smem[13760];
    __shared__ int   sSnd[64];
    float* sWaT  = smem;
    float* sWbT  = smem + 512;
    float* sMsg  = smem;
    float* sRb   = smem + 8704;
    float* sHidT = smem + 9216;

    int tid = threadIdx.x;

    if (tid < 64) {
        int idx = e_base + tid;
        int ok = idx < nlive;
        int e = ok ? elist[idx] : elist[nlive - 1];
        int snd = eidx[e];
        int rcv = eidx[EE + e];
        float vx = pos[rcv * 3 + 0] - pos[snd * 3 + 0] + shifts[e * 3 + 0];
        float vy = pos[rcv * 3 + 1] - pos[snd * 3 + 1] + shifts[e * 3 + 1];
        float vz = pos[rcv * 3 + 2] - pos[snd * 3 + 2] + shifts[e * 3 + 2];
        float r = sqrtf(vx * vx + vy * vy + vz * vz + 1e-12f);
        float rinv = 1.0f / r;
        float x = r * 0.2f;
        float x2 = x * x, x4 = x2 * x2, x5 = x4 * x;
        float env = 1.0f - 21.0f * x5 + 35.0f * x5 * x - 15.0f * x5 * x2;
        float pref = ok ? 0.632455532033676f * rinv * env : 0.0f;
        float s1, c1;
        __sincosf(0.62831853071795865f * r, &s1, &c1);
        float k2c = 2.0f * c1;
        float sp = 0.0f, sn = s1;
        #pragma unroll
        for (int b = 0; b < 8; b++) {
            sRb[b * 64 + tid] = pref * sn;
            float t = k2c * sn - sp; sp = sn; sn = t;
        }
        if (ok) ue4[idx] = make_float4(vx * rinv, vy * rinv, vz * rinv, 0.0f);
        sSnd[tid] = snd;
    }
    for (int idx = tid; idx < 512; idx += 256) {
        int b = idx >> 6, j = idx & 63;
        sWaT[j * 8 + b] = Wra[idx];
    }
    for (int idx = tid; idx < 64 * 128; idx += 256) {
        int j = idx >> 7, c = idx & 127;
        float v = Wrb[j * 256 + c] * (c < 64 ? 0.0625f : 0.10825317547305482f);
        int jb = j >> 2, jl = j & 3;
        int sj = ((jb ^ ((c >> 3) & 7)) << 2) | jl;
        sWbT[c * 64 + sj] = v;
    }
    __syncthreads();

    {
        int e = tid & 63, jg = tid >> 6;
        float rbv[8];
        #pragma unroll
        for (int b = 0; b < 8; b++) rbv[b] = sRb[b * 64 + e];
        const float4* waT4 = (const float4*)sWaT;
        float hid[16];
        #pragma unroll
        for (int jj = 0; jj < 16; jj++) {
            int j = jg * 16 + jj;
            float4 wa0 = waT4[j * 2 + 0];
            float4 wa1 = waT4[j * 2 + 1];
            float acc = rbv[0] * wa0.x + rbv[1] * wa0.y + rbv[2] * wa0.z + rbv[3] * wa0.w
                      + rbv[4] * wa1.x + rbv[5] * wa1.y + rbv[6] * wa1.z + rbv[7] * wa1.w;
            hid[jj] = silu_f(acc);
        }
        float4* hidT4 = (float4*)sHidT;
        int hk = (e >> 1) & 7;
        #pragma unroll
        for (int q = 0; q < 4; q++) {
            int j4 = jg * 4 + q;
            hidT4[e * 17 + (j4 ^ hk)] =
                make_float4(hid[q * 4 + 0], hid[q * 4 + 1], hid[q * 4 + 2], hid[q * 4 + 3]);
        }
    }
    __syncthreads();

    int cg = tid & 15, eg = tid >> 4;
    int e0 = eg * 4, c0 = cg * 8, cgl = cg & 7;
    const float4* hidT4 = (const float4*)sHidT;
    const float4* wbT4  = (const float4*)sWbT;
    int hk0 = ((e0 + 0) >> 1) & 7, hk1 = ((e0 + 1) >> 1) & 7;
    int hk2 = ((e0 + 2) >> 1) & 7, hk3 = ((e0 + 3) >> 1) & 7;
    float acc[4][8];
    #pragma unroll
    for (int i = 0; i < 4; i++)
        #pragma unroll
        for (int cc = 0; cc < 8; cc++) acc[i][cc] = 0.0f;

    for (int jb = 0; jb < 16; ++jb) {
        float4 h0_ = hidT4[(e0 + 0) * 17 + (jb ^ hk0)];
        float4 h1_ = hidT4[(e0 + 1) * 17 + (jb ^ hk1)];
        float4 h2_ = hidT4[(e0 + 2) * 17 + (jb ^ hk2)];
        float4 h3_ = hidT4[(e0 + 3) * 17 + (jb ^ hk3)];
        int wj = jb ^ cgl;
        #pragma unroll
        for (int cc = 0; cc < 8; cc++) {
            float4 wb = wbT4[(c0 + cc) * 16 + wj];
            acc[0][cc] += DOT4(h0_, wb);
            acc[1][cc] += DOT4(h1_, wb);
            acc[2][cc] += DOT4(h2_, wb);
            acc[3][cc] += DOT4(h3_, wb);
        }
    }
    __syncthreads();

    {
        float4* msg4 = (float4*)sMsg;
        #pragma unroll
        for (int i = 0; i < 4; ++i) {
            int e = e0 + i, xk = e & 7;
            msg4[e * 33 + ((2 * cg + 0) ^ xk)] =
                make_float4(acc[i][0], acc[i][1], acc[i][2], acc[i][3]);
            msg4[e * 33 + ((2 * cg + 1) ^ xk)] =
                make_float4(acc[i][4], acc[i][5], acc[i][6], acc[i][7]);
        }
    }
    __syncthreads();

    {
        int q = tid >> 6, c = tid & 63;
        #pragma unroll 4
        for (int i = 0; i < 16; ++i) {
            int e = q * 16 + i;
            int idx = e_base + e;
            if (idx >= nlive) continue;
            int snd = sSnd[e];
            float f = feats[(size_t)snd * CC + c];
            int xk = e & 7;
            float w0 = sMsg[e * 132 + (((c >> 2) ^ xk) << 2) + (c & 3)];
            float w1 = sMsg[e * 132 + (((16 + (c >> 2)) ^ xk) << 2) + (c & 3)];
            __half2 h = __floats2half2_rn(w0 * f, w1 * f);
            msg[(size_t)idx * 64 + c] = *(unsigned int*)&h;
        }
    }
}

// ---------------- streaming CSR gather: msg -> dense A[n,4,64] ----------------------
__global__ __launch_bounds__(256) void k_gather(
    const int* __restrict__ rowoff,
    const unsigned int* __restrict__ msg, const float4* __restrict__ ue4,
    float* __restrict__ A)
{
    int n = blockIdx.x * 4 + (threadIdx.x >> 6);
    int d = threadIdx.x & 63;
    int s0 = rowoff[n], s1 = rowoff[n + 1];
    float a0 = 0.f, ax = 0.f, ay = 0.f, az = 0.f;
    for (int s = s0; s < s1; ++s) {
        unsigned int mu = msg[(size_t)s * 64 + d];
        float4 u = ue4[s];
        float2 m = __half22float2(*(__half2*)&mu);
        a0 += m.x;
        ax = fmaf(m.y, u.x, ax);
        ay = fmaf(m.y, u.y, ay);
        az = fmaf(m.y, u.z, az);
    }
    float* Ar = A + (size_t)n * 256;
    Ar[d] = a0; Ar[64 + d] = ax; Ar[128 + d] = ay; Ar[192 + d] = az;
}

// ---------------- node update 1: 512 thr, 16 nodes/block, 2 re-staged buffers -------
__global__ __launch_bounds__(512) void node1(
    const int* __restrict__ elem, const float* __restrict__ A,
    const float* __restrict__ Wmix1, const float* __restrict__ sc1tab,
    const float* __restrict__ Wp1s, const float* __restrict__ Wp1v,
    const float* __restrict__ Wp10, const float* __restrict__ Wp11,
    const float* __restrict__ wrd1,
    float* __restrict__ out0, float* __restrict__ out1, float* __restrict__ d1)
{
    __shared__ float smem[12288];   // 48 KiB -> 3 blocks/CU
    float* sB0 = smem;
    float* sB1 = smem + 4096;
    float* sIn = smem + 8192;       // 16 nodes x 4 rows x 64

    int tid = threadIdx.x, w = tid >> 6, d = tid & 63;
    stage_wT(Wmix1,        sB0, tid, 512);
    stage_wT(Wmix1 + 4096, sB1, tid, 512);
    int nbase = blockIdx.x * 16;
    for (int idx = tid; idx < 4096; idx += 512)
        sIn[idx] = A[(size_t)nbase * 256 + idx];
    __syncthreads();

    const float4* sIn4 = (const float4*)sIn;
    int rbase = w * 8;
    int nloc = nbase + w * 2;

    float accs[2] = {0.f, 0.f};
    float acch[2][3];
    #pragma unroll
    for (int i = 0; i < 2; i++) acch[i][0] = acch[i][1] = acch[i][2] = 0.f;

    for (int c4 = 0; c4 < 16; ++c4) {
        float4 w0 = WREAD(sB0, d, c4);
        float4 w1 = WREAD(sB1, d, c4);
        #pragma unroll
        for (int i = 0; i < 2; ++i) {
            int rb = rbase + i * 4;
            float4 a0 = sIn4[(rb + 0) * 16 + c4];
            accs[i] += DOT4(a0, w0);
            float4 a1 = sIn4[(rb + 1) * 16 + c4]; acch[i][0] += DOT4(a1, w1);
            float4 a2 = sIn4[(rb + 2) * 16 + c4]; acch[i][1] += DOT4(a2, w1);
            float4 a3 = sIn4[(rb + 3) * 16 + c4]; acch[i][2] += DOT4(a3, w1);
        }
    }

    #pragma unroll
    for (int i = 0; i < 2; ++i) {
        int n = nloc + i, e = elem[n];
        float s = accs[i];
        float ws0 = Wp1s[e * 64 + d], ws1 = Wp1s[640 + e * 64 + d], ws2 = Wp1s[1280 + e * 64 + d];
        float wv0 = Wp1v[e * 64 + d], wv1 = Wp1v[640 + e * 64 + d], wv2 = Wp1v[1280 + e * 64 + d];
        float m0 = s * (ws0 + s * (ws1 + s * ws2));
        float gv = wv0 + s * (wv1 + s * wv2);
        int rb = rbase + i * 4;
        sIn[(rb + 0) * 64 + d] = m0;
        sIn[(rb + 1) * 64 + d] = acch[i][0] * gv;
        sIn[(rb + 2) * 64 + d] = acch[i][1] * gv;
        sIn[(rb + 3) * 64 + d] = acch[i][2] * gv;
    }
    __syncthreads();                // everyone done with sB0/sB1

    stage_wT(Wp10, sB0, tid, 512);
    stage_wT(Wp11, sB1, tid, 512);
    __syncthreads();

    float acc0[2] = {0.f, 0.f};
    float acc1[2][3];
    #pragma unroll
    for (int i = 0; i < 2; i++) acc1[i][0] = acc1[i][1] = acc1[i][2] = 0.f;

    for (int c4 = 0; c4 < 16; ++c4) {
        float4 p0 = WREAD(sB0, d, c4);
        float4 p1 = WREAD(sB1, d, c4);
        #pragma unroll
        for (int i = 0; i < 2; ++i) {
            int rb = rbase + i * 4;
            float4 a0 = sIn4[(rb + 0) * 16 + c4];
            acc0[i] += DOT4(a0, p0);
            float4 a1 = sIn4[(rb + 1) * 16 + c4]; acc1[i][0] += DOT4(a1, p1);
            float4 a2 = sIn4[(rb + 2) * 16 + c4]; acc1[i][1] += DOT4(a2, p1);
            float4 a3 = sIn4[(rb + 3) * 16 + c4]; acc1[i][2] += DOT4(a3, p1);
        }
    }

    float wr = wrd1[d];
    #pragma unroll
    for (int i = 0; i < 2; ++i) {
        int n = nloc + i, e = elem[n];
        out0[(size_t)n * 64 + d] = acc0[i] + sc1tab[e * 64 + d];
        #pragma unroll
        for (int m = 0; m < 3; ++m) {
            float o = acc1[i][m];
            out1[((size_t)n * 3 + m) * 64 + d] = o;
            float v = o * wr;
            v += __shfl_xor(v, 32); v += __shfl_xor(v, 16); v += __shfl_xor(v, 8);
            v += __shfl_xor(v, 4);  v += __shfl_xor(v, 2);  v += __shfl_xor(v, 1);
            if (d == 0) d1[n * 3 + m] = v;
        }
    }
}

// ---------------- node update 2: flat block map, 512 thr, 16 nodes/block -------------
__global__ __launch_bounds__(512) void node2(
    const int* __restrict__ belem, const int* __restrict__ bbase,
    const int* __restrict__ blim, const int* __restrict__ order,
    const float* __restrict__ A, const float* __restrict__ out1,
    const float* __restrict__ d1,
    const float* __restrict__ Wmix2, const float* __restrict__ Wsc2,
    const float* __restrict__ Wpr2, const float* __restrict__ Wp2,
    const float* __restrict__ Wv, const float* __restrict__ Wg1,
    const float* __restrict__ bg1, const float* __restrict__ Wg2,
    const float* __restrict__ bg2, const float* __restrict__ wrd2,
    const int* __restrict__ batch, const float* __restrict__ chg,
    const float* __restrict__ pos,
    float* __restrict__ total, float* __restrict__ dip)
{
    int b = blockIdx.x;
    int e = belem[b];
    if (e < 0) return;
    int base = bbase[b];
    int nv = blim[b] - base;

    __shared__ float smem[13312];   // 52 KiB -> 3 blocks/CU
    __shared__ int   sNid[16];
    __shared__ int   sVal[16];
    float* sB0 = smem;
    float* sB1 = smem + 4096;
    float* sWv = smem + 8192;       // 1024 floats
    float* sIn = smem + 9216;       // 4096 floats

    int tid = threadIdx.x, w = tid >> 6, d = tid & 63;
    if (tid < 16) {
        sVal[tid] = tid < nv;
        sNid[tid] = order[base + (tid < nv ? tid : nv - 1)];
    }
    stage_wT(Wmix2,        sB0, tid, 512);
    stage_wT(Wmix2 + 4096, sB1, tid, 512);
    for (int idx = tid; idx < 1024; idx += 512) {
        int h = idx & 15, c = idx >> 4;
        sWv[(h << 6) + ((((c >> 2) ^ h) << 2) | (c & 3))] = Wv[idx];
    }
    __syncthreads();
    for (int idx = tid; idx < 4096; idx += 512) {
        int row = idx >> 6, q = row >> 2, k = row & 3, dd = idx & 63;
        sIn[idx] = A[(size_t)sNid[q] * 256 + k * 64 + dd];
    }
    __syncthreads();

    const float4* sIn4 = (const float4*)sIn;
    int rbase = w * 8;

    float accs[2] = {0.f, 0.f};
    float acch[2][3];
    #pragma unroll
    for (int i = 0; i < 2; i++) acch[i][0] = acch[i][1] = acch[i][2] = 0.f;

    for (int c4 = 0; c4 < 16; ++c4) {
        float4 w0 = WREAD(sB0, d, c4);
        float4 w1 = WREAD(sB1, d, c4);
        #pragma unroll
        for (int i = 0; i < 2; ++i) {
            int rb = rbase + i * 4;
            float4 a0 = sIn4[(rb + 0) * 16 + c4];
            accs[i] += DOT4(a0, w0);
            float4 a1 = sIn4[(rb + 1) * 16 + c4]; acch[i][0] += DOT4(a1, w1);
            float4 a2 = sIn4[(rb + 2) * 16 + c4]; acch[i][1] += DOT4(a2, w1);
            float4 a3 = sIn4[(rb + 3) * 16 + c4]; acch[i][2] += DOT4(a3, w1);
        }
    }

    float wp0 = Wpr2[e * 64 + d], wp1 = Wpr2[640 + e * 64 + d], wp2_ = Wpr2[1280 + e * 64 + d];
    #pragma unroll
    for (int i = 0; i < 2; ++i) {
        float s2 = accs[i];
        float gv2 = wp0 + s2 * (wp1 + s2 * wp2_);
        int rb = rbase + i * 4;
        sIn[(rb + 1) * 64 + d] = acch[i][0] * gv2;
        sIn[(rb + 2) * 64 + d] = acch[i][1] * gv2;
        sIn[(rb + 3) * 64 + d] = acch[i][2] * gv2;
    }
    __syncthreads();                // everyone done with sB0/sB1

    stage_wT(Wp2,             sB0, tid, 512);
    stage_wT(Wsc2 + e * 4096, sB1, tid, 512);
    __syncthreads();

    float acc2[2][3];
    #pragma unroll
    for (int i = 0; i < 2; i++) acc2[i][0] = acc2[i][1] = acc2[i][2] = 0.f;
    const float4* o14 = (const float4*)out1;

    for (int c4 = 0; c4 < 16; ++c4) {
        float4 p = WREAD(sB0, d, c4);
        float4 s = WREAD(sB1, d, c4);
        #pragma unroll
        for (int i = 0; i < 2; ++i) {
            int rb = rbase + i * 4;
            size_t nq = (size_t)sNid[w * 2 + i];
            #pragma unroll
            for (int m = 0; m < 3; ++m) {
                float4 t  = sIn4[(rb + 1 + m) * 16 + c4];
                float4 o1 = o14[(nq * 3 + m) * 16 + c4];
                acc2[i][m] += DOT4(t, p) + DOT4(o1, s);
            }
        }
    }

    int m = d >> 4, h = d & 15;
    const float4* sWv4 = (const float4*)sWv;
    #pragma unroll
    for (int i = 0; i < 2; ++i) {
        int q = w * 2 + i, rb = rbase + i * 4;
        int n = sNid[q], valid = sVal[q];
        sIn[(rb + 1) * 64 + d] = acc2[i][0];
        sIn[(rb + 2) * 64 + d] = acc2[i][1];
        sIn[(rb + 3) * 64 + d] = acc2[i][2];

        float vh = 0.f;
        if (d < 48) {
            for (int c4 = 0; c4 < 16; ++c4) {
                float4 o2 = sIn4[(rb + 1 + m) * 16 + c4];
                float4 wv = sWv4[(h << 4) + (c4 ^ h)];
                vh += DOT4(o2, wv);
            }
            sIn[rb * 64 + m * 16 + h] = vh;
        }
        float* g = sIn + rb * 64;
        if (d < 16) {
            float v0 = g[d], v1 = g[16 + d], v2 = g[32 + d];
            g[48 + d] = sqrtf(v0 * v0 + v1 * v1 + v2 * v2 + 1e-12f);
        }
        if (d < 16) {
            float acc = bg1[d];
            for (int k = 0; k < 16; ++k) acc += g[48 + k] * Wg1[k * 16 + d];
            g[48 + d] = silu_f(acc);
        }
        if (d < 16) {
            float acc = bg2[d];
            for (int k = 0; k < 16; ++k) acc += g[48 + k] * Wg2[k * 16 + d];
            g[48 + d] = acc * wrd2[d];
        }
        if (d < 48) {
            float v = vh * g[48 + h];
            v += __shfl_xor(v, 8, 16); v += __shfl_xor(v, 4, 16);
            v += __shfl_xor(v, 2, 16); v += __shfl_xor(v, 1, 16);
            if (h == 0 && valid) {
                float dv = d1[n * 3 + m] + v;
                dip[n * 3 + m] = dv;
                atomicAdd(&total[batch[n] * 3 + m], dv + chg[n] * pos[n * 3 + m]);
            }
        }
    }
}

extern "C" void kernel_launch(void* const* d_in, const int* in_sizes, int n_in,
                              void* d_out, int out_size, void* d_ws, size_t ws_size,
                              hipStream_t stream) {
    const float* na     = (const float*)d_in[0];
    const float* pos    = (const float*)d_in[1];
    const float* shifts = (const float*)d_in[2];
    const float* chg    = (const float*)d_in[3];
    const int*   eidx   = (const int*)d_in[4];
    const int*   batch  = (const int*)d_in[5];
    const float* Wemb   = (const float*)d_in[7];
    const float* Wr1a   = (const float*)d_in[8];
    const float* Wr1b   = (const float*)d_in[9];
    const float* Wmix1  = (const float*)d_in[10];
    const float* Wsc1   = (const float*)d_in[11];
    const float* Wp1s   = (const float*)d_in[12];
    const float* Wp1v   = (const float*)d_in[13];
    const float* Wp10   = (const float*)d_in[14];
    const float* Wp11   = (const float*)d_in[15];
    const float* wrd1   = (const float*)d_in[16];
    const float* Wr2a   = (const float*)d_in[17];
    const float* Wr2b   = (const float*)d_in[18];
    const float* Wmix2  = (const float*)d_in[19];
    const float* Wsc2   = (const float*)d_in[20];
    const float* Wpr2   = (const float*)d_in[21];
    const float* Wp2    = (const float*)d_in[22];
    const float* Wv     = (const float*)d_in[23];
    const float* Wg1    = (const float*)d_in[24];
    const float* bg1    = (const float*)d_in[25];
    const float* Wg2    = (const float*)d_in[26];
    const float* bg2    = (const float*)d_in[27];
    const float* wrd2   = (const float*)d_in[28];

    // ---- workspace layout -----------------------------------------------------------
    unsigned int* msg = (unsigned int*)d_ws;                  // EE*64 (half2)
    float4* ue4  = (float4*)(msg + (size_t)EE * 64);          // EE
    float* A     = (float*)(ue4 + EE);                        // N*4*C
    float* h0    = A + (size_t)NN * 4 * CC;                   // N*C
    float* out0  = h0 + (size_t)NN * CC;                      // N*C
    float* out1  = out0 + (size_t)NN * CC;                    // N*3*C
    float* d1    = out1 + (size_t)NN * 3 * CC;                // N*3
    float* sc1t  = d1 + (size_t)NN * 3;                       // NEL*64
    int* elem    = (int*)(sc1t + NEL * 64);                   // N
    int* cnt     = elem + NN;                                 // NEL
    int* offs    = cnt + NEL;                                 // NEL
    int* curs    = offs + NEL;                                // NEL
    int* rowcnt  = curs + NEL;                                // N
    int* rowoff  = rowcnt + NN;                               // N+1
    int* rowcur  = rowoff + NN + 1;                           // N
    int* order   = rowcur + NN;                               // N
    int* elist   = order + NN;                                // E
    int* belem   = elist + EE;                                // NBLK2
    int* bbase   = belem + NBLK2;                             // NBLK2
    int* blim    = bbase + NBLK2;                             // NBLK2

    float* total = (float*)d_out;                             // G*3
    float* dip   = total + GG * 3;                            // N*3

    hipMemsetAsync(total, 0, (size_t)GG * 3 * sizeof(float), stream);
    hipMemsetAsync(cnt, 0, (size_t)(3 * NEL + NN) * sizeof(int), stream);

    k_h0<<<NN / 4, 256, 0, stream>>>(na, Wemb, h0, elem, cnt);
    k_csr_count<<<EE / 256, 256, 0, stream>>>(pos, shifts, eidx, rowcnt);
    k_scan<<<1, 1024, 0, stream>>>(rowcnt, rowoff, rowcur, cnt, offs, curs,
                                   belem, bbase, blim);
    k_csr_fill<<<EE / 256, 256, 0, stream>>>(pos, shifts, eidx, rowcur, elist);
    k_fill<<<NN / 256, 256, 0, stream>>>(elem, curs, order);
    k_sc1tab<<<NEL, 64, 0, stream>>>(Wemb, Wsc1, sc1t);

    edge_mlp<<<EE / 64, 256, 0, stream>>>(h0, pos, shifts, eidx, elist, rowoff,
                                          Wr1a, Wr1b, msg, ue4);
    k_gather<<<NN / 4, 256, 0, stream>>>(rowoff, msg, ue4, A);
    node1<<<NN / 16, 512, 0, stream>>>(elem, A, Wmix1, sc1t, Wp1s, Wp1v, Wp10, Wp11,
                                       wrd1, out0, out1, d1);
    edge_mlp<<<EE / 64, 256, 0, stream>>>(out0, pos, shifts, eidx, elist, rowoff,
                                          Wr2a, Wr2b, msg, ue4);
    k_gather<<<NN / 4, 256, 0, stream>>>(rowoff, msg, ue4, A);
    node2<<<NBLK2, 512, 0, stream>>>(belem, bbase, blim, order, A, out1, d1,
                                     Wmix2, Wsc2, Wpr2, Wp2, Wv, Wg1, bg1,
                                     Wg2, bg2, wrd2, batch, chg, pos,
                                     total, dip);
}

// Round 9
// 421.750 us; speedup vs baseline: 1.1380x; 1.1380x over previous
//
#include <hip/hip_runtime.h>
#include <hip/hip_fp16.h>
#include <math.h>

#define NN 8192
#define EE 131072
#define CC 64
#define GG 32
#define NEL 10
#define NBLK2 522

__device__ __forceinline__ float silu_f(float x) { return x / (1.0f + __expf(-x)); }

// stage a 64x64 row-major matrix W[c][d] into LDS transposed+XOR-swizzled
__device__ __forceinline__ void stage_wT(const float* __restrict__ W, float* sWT,
                                         int tid, int nt) {
    for (int idx = tid; idx < 4096; idx += nt) {
        int d = idx & 63, c = idx >> 6;
        sWT[(d << 6) + ((((c >> 2) ^ (d & 15)) << 2) | (c & 3))] = W[idx];
    }
}
#define WREAD(sWT, d, c4) (((const float4*)(sWT))[((d) << 4) + ((c4) ^ ((d) & 15))])
#define DOT4(a, b) ((a).x * (b).x + (a).y * (b).y + (a).z * (b).z + (a).w * (b).w)

// ---------------- h0 = W_embed[elem] ; elem = argmax ; element counts ---------------
__global__ __launch_bounds__(256) void k_h0(const float* __restrict__ na,
                                            const float* __restrict__ Wemb,
                                            float* __restrict__ h0,
                                            int* __restrict__ elem,
                                            int* __restrict__ cnt) {
    int n = blockIdx.x * 4 + (threadIdx.x >> 6);
    int d = threadIdx.x & 63;
    float acc = 0.0f;
    float best = -1.0f; int bi = 0;
    #pragma unroll
    for (int k = 0; k < NEL; k++) {
        float a = na[n * NEL + k];
        acc += a * Wemb[k * 64 + d];
        if (a > best) { best = a; bi = k; }
    }
    h0[n * 64 + d] = acc;
    if (d == 0) { elem[n] = bi; atomicAdd(&cnt[bi], 1); }
}

// ---------------- sc1 lookup table: sc1tab[e] = W_embed[e] @ Wsc1[e] ----------------
__global__ __launch_bounds__(64) void k_sc1tab(const float* __restrict__ Wemb,
                                               const float* __restrict__ Wsc1,
                                               float* __restrict__ tab) {
    int e = blockIdx.x, d = threadIdx.x;
    float acc = 0.0f;
    for (int c = 0; c < 64; c++)
        acc += Wemb[e * 64 + c] * Wsc1[e * 4096 + c * 64 + d];
    tab[e * 64 + d] = acc;
}

__global__ __launch_bounds__(256) void k_fill(const int* __restrict__ elem,
                                              int* cursor, int* __restrict__ order) {
    int n = blockIdx.x * 256 + threadIdx.x;
    int p = atomicAdd(&cursor[elem[n]], 1);
    order[p] = n;
}

// ---------------- CSR build over LIVE edges -----------------------------------------
__device__ __forceinline__ int edge_live(const float* pos, const float* shifts,
                                         const int* eidx, int e, int* rcv_out) {
    int snd = eidx[e];
    int rcv = eidx[EE + e];
    float vx = pos[rcv * 3 + 0] - pos[snd * 3 + 0] + shifts[e * 3 + 0];
    float vy = pos[rcv * 3 + 1] - pos[snd * 3 + 1] + shifts[e * 3 + 1];
    float vz = pos[rcv * 3 + 2] - pos[snd * 3 + 2] + shifts[e * 3 + 2];
    float r = sqrtf(vx * vx + vy * vy + vz * vz + 1e-12f);
    *rcv_out = rcv;
    return (r * 0.2f) < 1.0f;
}
__global__ __launch_bounds__(256) void k_csr_count(const float* __restrict__ pos,
                                                   const float* __restrict__ shifts,
                                                   const int* __restrict__ eidx,
                                                   int* __restrict__ rowcnt) {
    int e = blockIdx.x * 256 + threadIdx.x;
    int rcv;
    if (edge_live(pos, shifts, eidx, e, &rcv)) atomicAdd(&rowcnt[rcv], 1);
}
// scan rowcnt -> rowoff/rowcur ; element cnt -> offs/curs ; build node2 block map
__global__ __launch_bounds__(1024) void k_scan(const int* __restrict__ rowcnt,
                                               int* __restrict__ rowoff,
                                               int* __restrict__ rowcur,
                                               const int* __restrict__ cnt,
                                               int* __restrict__ offs,
                                               int* __restrict__ curs,
                                               int* __restrict__ belem,
                                               int* __restrict__ bbase,
                                               int* __restrict__ blim) {
    __shared__ int part[1024];
    int t = threadIdx.x;
    if (t < NBLK2) belem[t] = -1;
    int loc[8]; int s = 0;
    #pragma unroll
    for (int k = 0; k < 8; k++) { loc[k] = rowcnt[t * 8 + k]; s += loc[k]; }
    part[t] = s;
    __syncthreads();
    for (int d = 1; d < 1024; d <<= 1) {
        int v = (t >= d) ? part[t - d] : 0;
        __syncthreads();
        part[t] += v;
        __syncthreads();
    }
    int run = (t > 0) ? part[t - 1] : 0;
    #pragma unroll
    for (int k = 0; k < 8; k++) {
        rowoff[t * 8 + k] = run; rowcur[t * 8 + k] = run; run += loc[k];
    }
    if (t == 1023) rowoff[8192] = run;
    __syncthreads();
    if (t == 0) {
        int s2 = 0, b = 0;
        for (int e = 0; e < NEL; e++) {
            offs[e] = s2; curs[e] = s2;
            int c = cnt[e];
            for (int q = 0; q < c; q += 16) {
                belem[b] = e;
                bbase[b] = s2 + q;
                blim[b] = s2 + ((q + 16 < c) ? (q + 16) : c);
                b++;
            }
            s2 += c;
        }
    }
}
__global__ __launch_bounds__(256) void k_csr_fill(const float* __restrict__ pos,
                                                  const float* __restrict__ shifts,
                                                  const int* __restrict__ eidx,
                                                  int* __restrict__ rowcur,
                                                  int* __restrict__ elist) {
    int e = blockIdx.x * 256 + threadIdx.x;
    int rcv;
    if (edge_live(pos, shifts, eidx, e, &rcv)) {
        int p = atomicAdd(&rowcur[rcv], 1);
        elist[p] = e;
    }
}

// ---------------- edge MLP over CSR-ordered LIVE edges ------------------------------
__global__ __launch_bounds__(256) void edge_mlp(
    const float* __restrict__ feats, const float* __restrict__ pos,
    const float* __restrict__ shifts, const int* __restrict__ eidx,
    const int* __restrict__ elist, const int* __restrict__ rowoff,
    const float* __restrict__ Wra, const float* __restrict__ Wrb,
    unsigned int* __restrict__ msg, float4* __restrict__ ue4)
{
    int nlive = rowoff[NN];
    int e_base = blockIdx.x * 64;
    if (e_base >= nlive) return;

    __shared__ float smem[13760];
    __shared__ int   sSnd[64];
    float* sWaT  = smem;
    float* sWbT  = smem + 512;
    float* sMsg  = smem;
    float* sRb   = smem + 8704;
    float* sHidT = smem + 9216;

    int tid = threadIdx.x;

    if (tid < 64) {
        int idx = e_base + tid;
        int ok = idx < nlive;
        int e = ok ? elist[idx] : elist[nlive - 1];
        int snd = eidx[e];
        int rcv = eidx[EE + e];
        float vx = pos[rcv * 3 + 0] - pos[snd * 3 + 0] + shifts[e * 3 + 0];
        float vy = pos[rcv * 3 + 1] - pos[snd * 3 + 1] + shifts[e * 3 + 1];
        float vz = pos[rcv * 3 + 2] - pos[snd * 3 + 2] + shifts[e * 3 + 2];
        float r = sqrtf(vx * vx + vy * vy + vz * vz + 1e-12f);
        float rinv = 1.0f / r;
        float x = r * 0.2f;
        float x2 = x * x, x4 = x2 * x2, x5 = x4 * x;
        float env = 1.0f - 21.0f * x5 + 35.0f * x5 * x - 15.0f * x5 * x2;
        float pref = ok ? 0.632455532033676f * rinv * env : 0.0f;
        float s1, c1;
        __sincosf(0.62831853071795865f * r, &s1, &c1);
        float k2c = 2.0f * c1;
        float sp = 0.0f, sn = s1;
        #pragma unroll
        for (int b = 0; b < 8; b++) {
            sRb[b * 64 + tid] = pref * sn;
            float t = k2c * sn - sp; sp = sn; sn = t;
        }
        if (ok) ue4[idx] = make_float4(vx * rinv, vy * rinv, vz * rinv, 0.0f);
        sSnd[tid] = snd;
    }
    for (int idx = tid; idx < 512; idx += 256) {
        int b = idx >> 6, j = idx & 63;
        sWaT[j * 8 + b] = Wra[idx];
    }
    for (int idx = tid; idx < 64 * 128; idx += 256) {
        int j = idx >> 7, c = idx & 127;
        float v = Wrb[j * 256 + c] * (c < 64 ? 0.0625f : 0.10825317547305482f);
        int jb = j >> 2, jl = j & 3;
        int sj = ((jb ^ ((c >> 3) & 7)) << 2) | jl;
        sWbT[c * 64 + sj] = v;
    }
    __syncthreads();

    {
        int e = tid & 63, jg = tid >> 6;
        float rbv[8];
        #pragma unroll
        for (int b = 0; b < 8; b++) rbv[b] = sRb[b * 64 + e];
        const float4* waT4 = (const float4*)sWaT;
        float hid[16];
        #pragma unroll
        for (int jj = 0; jj < 16; jj++) {
            int j = jg * 16 + jj;
            float4 wa0 = waT4[j * 2 + 0];
            float4 wa1 = waT4[j * 2 + 1];
            float acc = rbv[0] * wa0.x + rbv[1] * wa0.y + rbv[2] * wa0.z + rbv[3] * wa0.w
                      + rbv[4] * wa1.x + rbv[5] * wa1.y + rbv[6] * wa1.z + rbv[7] * wa1.w;
            hid[jj] = silu_f(acc);
        }
        float4* hidT4 = (float4*)sHidT;
        int hk = (e >> 1) & 7;
        #pragma unroll
        for (int q = 0; q < 4; q++) {
            int j4 = jg * 4 + q;
            hidT4[e * 17 + (j4 ^ hk)] =
                make_float4(hid[q * 4 + 0], hid[q * 4 + 1], hid[q * 4 + 2], hid[q * 4 + 3]);
        }
    }
    __syncthreads();

    int cg = tid & 15, eg = tid >> 4;
    int e0 = eg * 4, c0 = cg * 8, cgl = cg & 7;
    const float4* hidT4 = (const float4*)sHidT;
    const float4* wbT4  = (const float4*)sWbT;
    int hk0 = ((e0 + 0) >> 1) & 7, hk1 = ((e0 + 1) >> 1) & 7;
    int hk2 = ((e0 + 2) >> 1) & 7, hk3 = ((e0 + 3) >> 1) & 7;
    float acc[4][8];
    #pragma unroll
    for (int i = 0; i < 4; i++)
        #pragma unroll
        for (int cc = 0; cc < 8; cc++) acc[i][cc] = 0.0f;

    for (int jb = 0; jb < 16; ++jb) {
        float4 h0_ = hidT4[(e0 + 0) * 17 + (jb ^ hk0)];
        float4 h1_ = hidT4[(e0 + 1) * 17 + (jb ^ hk1)];
        float4 h2_ = hidT4[(e0 + 2) * 17 + (jb ^ hk2)];
        float4 h3_ = hidT4[(e0 + 3) * 17 + (jb ^ hk3)];
        int wj = jb ^ cgl;
        #pragma unroll
        for (int cc = 0; cc < 8; cc++) {
            float4 wb = wbT4[(c0 + cc) * 16 + wj];
            acc[0][cc] += DOT4(h0_, wb);
            acc[1][cc] += DOT4(h1_, wb);
            acc[2][cc] += DOT4(h2_, wb);
            acc[3][cc] += DOT4(h3_, wb);
        }
    }
    __syncthreads();

    {
        float4* msg4 = (float4*)sMsg;
        #pragma unroll
        for (int i = 0; i < 4; ++i) {
            int e = e0 + i, xk = e & 7;
            msg4[e * 33 + ((2 * cg + 0) ^ xk)] =
                make_float4(acc[i][0], acc[i][1], acc[i][2], acc[i][3]);
            msg4[e * 33 + ((2 * cg + 1) ^ xk)] =
                make_float4(acc[i][4], acc[i][5], acc[i][6], acc[i][7]);
        }
    }
    __syncthreads();

    {
        int q = tid >> 6, c = tid & 63;
        #pragma unroll 4
        for (int i = 0; i < 16; ++i) {
            int e = q * 16 + i;
            int idx = e_base + e;
            if (idx >= nlive) continue;
            int snd = sSnd[e];
            float f = feats[(size_t)snd * CC + c];
            int xk = e & 7;
            float w0 = sMsg[e * 132 + (((c >> 2) ^ xk) << 2) + (c & 3)];
            float w1 = sMsg[e * 132 + (((16 + (c >> 2)) ^ xk) << 2) + (c & 3)];
            __half2 h = __floats2half2_rn(w0 * f, w1 * f);
            msg[(size_t)idx * 64 + c] = *(unsigned int*)&h;
        }
    }
}

// ---------------- streaming CSR gather: msg -> dense A[n,4,64] ----------------------
__global__ __launch_bounds__(256) void k_gather(
    const int* __restrict__ rowoff,
    const unsigned int* __restrict__ msg, const float4* __restrict__ ue4,
    float* __restrict__ A)
{
    int n = blockIdx.x * 4 + (threadIdx.x >> 6);
    int d = threadIdx.x & 63;
    int s0 = rowoff[n], s1 = rowoff[n + 1];
    float a0 = 0.f, ax = 0.f, ay = 0.f, az = 0.f;
    for (int s = s0; s < s1; ++s) {
        unsigned int mu = msg[(size_t)s * 64 + d];
        float4 u = ue4[s];
        float2 m = __half22float2(*(__half2*)&mu);
        a0 += m.x;
        ax = fmaf(m.y, u.x, ax);
        ay = fmaf(m.y, u.y, ay);
        az = fmaf(m.y, u.z, az);
    }
    float* Ar = A + (size_t)n * 256;
    Ar[d] = a0; Ar[64 + d] = ax; Ar[128 + d] = ay; Ar[192 + d] = az;
}

// ---------------- node update 1: 8 nodes/block (2 per wave), 4 buffers, no restage --
__global__ __launch_bounds__(256) void node1(
    const int* __restrict__ elem, const float* __restrict__ A,
    const float* __restrict__ Wmix1, const float* __restrict__ sc1tab,
    const float* __restrict__ Wp1s, const float* __restrict__ Wp1v,
    const float* __restrict__ Wp10, const float* __restrict__ Wp11,
    const float* __restrict__ wrd1,
    float* __restrict__ out0, float* __restrict__ out1, float* __restrict__ d1)
{
    __shared__ float smem[18432];   // 72 KiB
    float* sW0 = smem;
    float* sW1 = smem + 4096;
    float* sP0 = smem + 8192;
    float* sP1 = smem + 12288;
    float* sIn = smem + 16384;      // 8 nodes x 4 rows x 64

    int tid = threadIdx.x, w = tid >> 6, d = tid & 63;
    stage_wT(Wmix1,        sW0, tid, 256);
    stage_wT(Wmix1 + 4096, sW1, tid, 256);
    stage_wT(Wp10,         sP0, tid, 256);
    stage_wT(Wp11,         sP1, tid, 256);
    int nbase = blockIdx.x * 8;
    for (int idx = tid; idx < 2048; idx += 256)
        sIn[idx] = A[(size_t)nbase * 256 + idx];
    __syncthreads();

    const float4* sIn4 = (const float4*)sIn;
    int rbase = w * 8;
    int nloc = nbase + w * 2;

    float accs[2] = {0.f, 0.f};
    float acch[2][3];
    #pragma unroll
    for (int i = 0; i < 2; i++) acch[i][0] = acch[i][1] = acch[i][2] = 0.f;

    for (int c4 = 0; c4 < 16; ++c4) {
        float4 w0 = WREAD(sW0, d, c4);
        float4 w1 = WREAD(sW1, d, c4);
        #pragma unroll
        for (int i = 0; i < 2; ++i) {
            int rb = rbase + i * 4;
            float4 a0 = sIn4[(rb + 0) * 16 + c4];
            accs[i] += DOT4(a0, w0);
            float4 a1 = sIn4[(rb + 1) * 16 + c4]; acch[i][0] += DOT4(a1, w1);
            float4 a2 = sIn4[(rb + 2) * 16 + c4]; acch[i][1] += DOT4(a2, w1);
            float4 a3 = sIn4[(rb + 3) * 16 + c4]; acch[i][2] += DOT4(a3, w1);
        }
    }

    #pragma unroll
    for (int i = 0; i < 2; ++i) {
        int n = nloc + i, e = elem[n];
        float s = accs[i];
        float ws0 = Wp1s[e * 64 + d], ws1 = Wp1s[640 + e * 64 + d], ws2 = Wp1s[1280 + e * 64 + d];
        float wv0 = Wp1v[e * 64 + d], wv1 = Wp1v[640 + e * 64 + d], wv2 = Wp1v[1280 + e * 64 + d];
        float m0 = s * (ws0 + s * (ws1 + s * ws2));
        float gv = wv0 + s * (wv1 + s * wv2);
        int rb = rbase + i * 4;
        sIn[(rb + 0) * 64 + d] = m0;
        sIn[(rb + 1) * 64 + d] = acch[i][0] * gv;
        sIn[(rb + 2) * 64 + d] = acch[i][1] * gv;
        sIn[(rb + 3) * 64 + d] = acch[i][2] * gv;
    }

    float acc0[2] = {0.f, 0.f};
    float acc1[2][3];
    #pragma unroll
    for (int i = 0; i < 2; i++) acc1[i][0] = acc1[i][1] = acc1[i][2] = 0.f;

    for (int c4 = 0; c4 < 16; ++c4) {
        float4 p0 = WREAD(sP0, d, c4);
        float4 p1 = WREAD(sP1, d, c4);
        #pragma unroll
        for (int i = 0; i < 2; ++i) {
            int rb = rbase + i * 4;
            float4 a0 = sIn4[(rb + 0) * 16 + c4];
            acc0[i] += DOT4(a0, p0);
            float4 a1 = sIn4[(rb + 1) * 16 + c4]; acc1[i][0] += DOT4(a1, p1);
            float4 a2 = sIn4[(rb + 2) * 16 + c4]; acc1[i][1] += DOT4(a2, p1);
            float4 a3 = sIn4[(rb + 3) * 16 + c4]; acc1[i][2] += DOT4(a3, p1);
        }
    }

    float wr = wrd1[d];
    #pragma unroll
    for (int i = 0; i < 2; ++i) {
        int n = nloc + i, e = elem[n];
        out0[(size_t)n * 64 + d] = acc0[i] + sc1tab[e * 64 + d];
        #pragma unroll
        for (int m = 0; m < 3; ++m) {
            float o = acc1[i][m];
            out1[((size_t)n * 3 + m) * 64 + d] = o;
            float v = o * wr;
            v += __shfl_xor(v, 32); v += __shfl_xor(v, 16); v += __shfl_xor(v, 8);
            v += __shfl_xor(v, 4);  v += __shfl_xor(v, 2);  v += __shfl_xor(v, 1);
            if (d == 0) d1[n * 3 + m] = v;
        }
    }
}

// ---------------- node update 2: flat block map, 512 thr, 16 nodes/block -------------
__global__ __launch_bounds__(512) void node2(
    const int* __restrict__ belem, const int* __restrict__ bbase,
    const int* __restrict__ blim, const int* __restrict__ order,
    const float* __restrict__ A, const float* __restrict__ out1,
    const float* __restrict__ d1,
    const float* __restrict__ Wmix2, const float* __restrict__ Wsc2,
    const float* __restrict__ Wpr2, const float* __restrict__ Wp2,
    const float* __restrict__ Wv, const float* __restrict__ Wg1,
    const float* __restrict__ bg1, const float* __restrict__ Wg2,
    const float* __restrict__ bg2, const float* __restrict__ wrd2,
    const int* __restrict__ batch, const float* __restrict__ chg,
    const float* __restrict__ pos,
    float* __restrict__ total, float* __restrict__ dip)
{
    int b = blockIdx.x;
    int e = belem[b];
    if (e < 0) return;
    int base = bbase[b];
    int nv = blim[b] - base;

    __shared__ float smem[13312];   // 52 KiB -> 3 blocks/CU
    __shared__ int   sNid[16];
    __shared__ int   sVal[16];
    float* sB0 = smem;
    float* sB1 = smem + 4096;
    float* sWv = smem + 8192;       // 1024 floats
    float* sIn = smem + 9216;       // 4096 floats

    int tid = threadIdx.x, w = tid >> 6, d = tid & 63;
    if (tid < 16) {
        sVal[tid] = tid < nv;
        sNid[tid] = order[base + (tid < nv ? tid : nv - 1)];
    }
    stage_wT(Wmix2,        sB0, tid, 512);
    stage_wT(Wmix2 + 4096, sB1, tid, 512);
    for (int idx = tid; idx < 1024; idx += 512) {
        int h = idx & 15, c = idx >> 4;
        sWv[(h << 6) + ((((c >> 2) ^ h) << 2) | (c & 3))] = Wv[idx];
    }
    __syncthreads();
    for (int idx = tid; idx < 4096; idx += 512) {
        int row = idx >> 6, q = row >> 2, k = row & 3, dd = idx & 63;
        sIn[idx] = A[(size_t)sNid[q] * 256 + k * 64 + dd];
    }
    __syncthreads();

    const float4* sIn4 = (const float4*)sIn;
    int rbase = w * 8;

    float accs[2] = {0.f, 0.f};
    float acch[2][3];
    #pragma unroll
    for (int i = 0; i < 2; i++) acch[i][0] = acch[i][1] = acch[i][2] = 0.f;

    for (int c4 = 0; c4 < 16; ++c4) {
        float4 w0 = WREAD(sB0, d, c4);
        float4 w1 = WREAD(sB1, d, c4);
        #pragma unroll
        for (int i = 0; i < 2; ++i) {
            int rb = rbase + i * 4;
            float4 a0 = sIn4[(rb + 0) * 16 + c4];
            accs[i] += DOT4(a0, w0);
            float4 a1 = sIn4[(rb + 1) * 16 + c4]; acch[i][0] += DOT4(a1, w1);
            float4 a2 = sIn4[(rb + 2) * 16 + c4]; acch[i][1] += DOT4(a2, w1);
            float4 a3 = sIn4[(rb + 3) * 16 + c4]; acch[i][2] += DOT4(a3, w1);
        }
    }

    float wp0 = Wpr2[e * 64 + d], wp1 = Wpr2[640 + e * 64 + d], wp2_ = Wpr2[1280 + e * 64 + d];
    #pragma unroll
    for (int i = 0; i < 2; ++i) {
        float s2 = accs[i];
        float gv2 = wp0 + s2 * (wp1 + s2 * wp2_);
        int rb = rbase + i * 4;
        sIn[(rb + 1) * 64 + d] = acch[i][0] * gv2;
        sIn[(rb + 2) * 64 + d] = acch[i][1] * gv2;
        sIn[(rb + 3) * 64 + d] = acch[i][2] * gv2;
    }
    __syncthreads();                // everyone done with sB0/sB1

    stage_wT(Wp2,             sB0, tid, 512);
    stage_wT(Wsc2 + e * 4096, sB1, tid, 512);
    __syncthreads();

    float acc2[2][3];
    #pragma unroll
    for (int i = 0; i < 2; i++) acc2[i][0] = acc2[i][1] = acc2[i][2] = 0.f;
    const float4* o14 = (const float4*)out1;

    for (int c4 = 0; c4 < 16; ++c4) {
        float4 p = WREAD(sB0, d, c4);
        float4 s = WREAD(sB1, d, c4);
        #pragma unroll
        for (int i = 0; i < 2; ++i) {
            int rb = rbase + i * 4;
            size_t nq = (size_t)sNid[w * 2 + i];
            #pragma unroll
            for (int m = 0; m < 3; ++m) {
                float4 t  = sIn4[(rb + 1 + m) * 16 + c4];
                float4 o1 = o14[(nq * 3 + m) * 16 + c4];
                acc2[i][m] += DOT4(t, p) + DOT4(o1, s);
            }
        }
    }

    int m = d >> 4, h = d & 15;
    const float4* sWv4 = (const float4*)sWv;
    #pragma unroll
    for (int i = 0; i < 2; ++i) {
        int q = w * 2 + i, rb = rbase + i * 4;
        int n = sNid[q], valid = sVal[q];
        sIn[(rb + 1) * 64 + d] = acc2[i][0];
        sIn[(rb + 2) * 64 + d] = acc2[i][1];
        sIn[(rb + 3) * 64 + d] = acc2[i][2];

        float vh = 0.f;
        if (d < 48) {
            for (int c4 = 0; c4 < 16; ++c4) {
                float4 o2 = sIn4[(rb + 1 + m) * 16 + c4];
                float4 wv = sWv4[(h << 4) + (c4 ^ h)];
                vh += DOT4(o2, wv);
            }
            sIn[rb * 64 + m * 16 + h] = vh;
        }
        float* g = sIn + rb * 64;
        if (d < 16) {
            float v0 = g[d], v1 = g[16 + d], v2 = g[32 + d];
            g[48 + d] = sqrtf(v0 * v0 + v1 * v1 + v2 * v2 + 1e-12f);
        }
        if (d < 16) {
            float acc = bg1[d];
            for (int k = 0; k < 16; ++k) acc += g[48 + k] * Wg1[k * 16 + d];
            g[48 + d] = silu_f(acc);
        }
        if (d < 16) {
            float acc = bg2[d];
            for (int k = 0; k < 16; ++k) acc += g[48 + k] * Wg2[k * 16 + d];
            g[48 + d] = acc * wrd2[d];
        }
        if (d < 48) {
            float v = vh * g[48 + h];
            v += __shfl_xor(v, 8, 16); v += __shfl_xor(v, 4, 16);
            v += __shfl_xor(v, 2, 16); v += __shfl_xor(v, 1, 16);
            if (h == 0 && valid) {
                float dv = d1[n * 3 + m] + v;
                dip[n * 3 + m] = dv;
                atomicAdd(&total[batch[n] * 3 + m], dv + chg[n] * pos[n * 3 + m]);
            }
        }
    }
}

extern "C" void kernel_launch(void* const* d_in, const int* in_sizes, int n_in,
                              void* d_out, int out_size, void* d_ws, size_t ws_size,
                              hipStream_t stream) {
    const float* na     = (const float*)d_in[0];
    const float* pos    = (const float*)d_in[1];
    const float* shifts = (const float*)d_in[2];
    const float* chg    = (const float*)d_in[3];
    const int*   eidx   = (const int*)d_in[4];
    const int*   batch  = (const int*)d_in[5];
    const float* Wemb   = (const float*)d_in[7];
    const float* Wr1a   = (const float*)d_in[8];
    const float* Wr1b   = (const float*)d_in[9];
    const float* Wmix1  = (const float*)d_in[10];
    const float* Wsc1   = (const float*)d_in[11];
    const float* Wp1s   = (const float*)d_in[12];
    const float* Wp1v   = (const float*)d_in[13];
    const float* Wp10   = (const float*)d_in[14];
    const float* Wp11   = (const float*)d_in[15];
    const float* wrd1   = (const float*)d_in[16];
    const float* Wr2a   = (const float*)d_in[17];
    const float* Wr2b   = (const float*)d_in[18];
    const float* Wmix2  = (const float*)d_in[19];
    const float* Wsc2   = (const float*)d_in[20];
    const float* Wpr2   = (const float*)d_in[21];
    const float* Wp2    = (const float*)d_in[22];
    const float* Wv     = (const float*)d_in[23];
    const float* Wg1    = (const float*)d_in[24];
    const float* bg1    = (const float*)d_in[25];
    const float* Wg2    = (const float*)d_in[26];
    const float* bg2    = (const float*)d_in[27];
    const float* wrd2   = (const float*)d_in[28];

    // ---- workspace layout -----------------------------------------------------------
    unsigned int* msg = (unsigned int*)d_ws;                  // EE*64 (half2)
    float4* ue4  = (float4*)(msg + (size_t)EE * 64);          // EE
    float* A     = (float*)(ue4 + EE);                        // N*4*C
    float* h0    = A + (size_t)NN * 4 * CC;                   // N*C
    float* out0  = h0 + (size_t)NN * CC;                      // N*C
    float* out1  = out0 + (size_t)NN * CC;                    // N*3*C
    float* d1    = out1 + (size_t)NN * 3 * CC;                // N*3
    float* sc1t  = d1 + (size_t)NN * 3;                       // NEL*64
    int* elem    = (int*)(sc1t + NEL * 64);                   // N
    int* cnt     = elem + NN;                                 // NEL
    int* offs    = cnt + NEL;                                 // NEL
    int* curs    = offs + NEL;                                // NEL
    int* rowcnt  = curs + NEL;                                // N
    int* rowoff  = rowcnt + NN;                               // N+1
    int* rowcur  = rowoff + NN + 1;                           // N
    int* order   = rowcur + NN;                               // N
    int* elist   = order + NN;                                // E
    int* belem   = elist + EE;                                // NBLK2
    int* bbase   = belem + NBLK2;                             // NBLK2
    int* blim    = bbase + NBLK2;                             // NBLK2

    float* total = (float*)d_out;                             // G*3
    float* dip   = total + GG * 3;                            // N*3

    hipMemsetAsync(total, 0, (size_t)GG * 3 * sizeof(float), stream);
    hipMemsetAsync(cnt, 0, (size_t)(3 * NEL + NN) * sizeof(int), stream);

    k_h0<<<NN / 4, 256, 0, stream>>>(na, Wemb, h0, elem, cnt);
    k_csr_count<<<EE / 256, 256, 0, stream>>>(pos, shifts, eidx, rowcnt);
    k_scan<<<1, 1024, 0, stream>>>(rowcnt, rowoff, rowcur, cnt, offs, curs,
                                   belem, bbase, blim);
    k_csr_fill<<<EE / 256, 256, 0, stream>>>(pos, shifts, eidx, rowcur, elist);
    k_fill<<<NN / 256, 256, 0, stream>>>(elem, curs, order);
    k_sc1tab<<<NEL, 64, 0, stream>>>(Wemb, Wsc1, sc1t);

    edge_mlp<<<EE / 64, 256, 0, stream>>>(h0, pos, shifts, eidx, elist, rowoff,
                                          Wr1a, Wr1b, msg, ue4);
    k_gather<<<NN / 4, 256, 0, stream>>>(rowoff, msg, ue4, A);
    node1<<<NN / 8, 256, 0, stream>>>(elem, A, Wmix1, sc1t, Wp1s, Wp1v, Wp10, Wp11,
                                      wrd1, out0, out1, d1);
    edge_mlp<<<EE / 64, 256, 0, stream>>>(out0, pos, shifts, eidx, elist, rowoff,
                                          Wr2a, Wr2b, msg, ue4);
    k_gather<<<NN / 4, 256, 0, stream>>>(rowoff, msg, ue4, A);
    node2<<<NBLK2, 512, 0, stream>>>(belem, bbase, blim, order, A, out1, d1,
                                     Wmix2, Wsc2, Wpr2, Wp2, Wv, Wg1, bg1,
                                     Wg2, bg2, wrd2, batch, chg, pos,
                                     total, dip);
}

// Round 10
// 282.726 us; speedup vs baseline: 1.6975x; 1.4917x over previous
//
#include <hip/hip_runtime.h>
#include <hip/hip_fp16.h>
#include <math.h>

#define NN 8192
#define EE 131072
#define CC 64
#define GG 32
#define NEL 10
#define NBLK2 522
#define NHB 32          // histogram blocks (NN/256)

__device__ __forceinline__ float silu_f(float x) { return x / (1.0f + __expf(-x)); }

// stage a 64x64 row-major matrix W[c][d] into LDS transposed+XOR-swizzled
__device__ __forceinline__ void stage_wT(const float* __restrict__ W, float* sWT,
                                         int tid, int nt) {
    for (int idx = tid; idx < 4096; idx += nt) {
        int d = idx & 63, c = idx >> 6;
        sWT[(d << 6) + ((((c >> 2) ^ (d & 15)) << 2) | (c & 3))] = W[idx];
    }
}
#define WREAD(sWT, d, c4) (((const float4*)(sWT))[((d) << 4) + ((c4) ^ ((d) & 15))])
#define DOT4(a, b) ((a).x * (b).x + (a).y * (b).y + (a).z * (b).z + (a).w * (b).w)

// ---------------- h0 = W_embed[elem] ; elem = argmax (no atomics) -------------------
__global__ __launch_bounds__(256) void k_h0(const float* __restrict__ na,
                                            const float* __restrict__ Wemb,
                                            float* __restrict__ h0,
                                            int* __restrict__ elem) {
    int n = blockIdx.x * 4 + (threadIdx.x >> 6);
    int d = threadIdx.x & 63;
    float acc = 0.0f;
    float best = -1.0f; int bi = 0;
    #pragma unroll
    for (int k = 0; k < NEL; k++) {
        float a = na[n * NEL + k];
        acc += a * Wemb[k * 64 + d];
        if (a > best) { best = a; bi = k; }
    }
    h0[n * 64 + d] = acc;
    if (d == 0) elem[n] = bi;
}

// ---------------- per-block element histogram (LDS atomics only) --------------------
__global__ __launch_bounds__(256) void k_hist(const int* __restrict__ elem,
                                              int* __restrict__ bhist) {
    __shared__ int h[NEL];
    int t = threadIdx.x;
    if (t < NEL) h[t] = 0;
    __syncthreads();
    atomicAdd(&h[elem[blockIdx.x * 256 + t]], 1);
    __syncthreads();
    if (t < NEL) bhist[blockIdx.x * NEL + t] = h[t];
}

// ---------------- counting-sort fill (LDS cursors, no global contention) ------------
__global__ __launch_bounds__(256) void k_fill(const int* __restrict__ elem,
                                              const int* __restrict__ bbase2,
                                              int* __restrict__ order) {
    __shared__ int cur[NEL];
    int t = threadIdx.x;
    if (t < NEL) cur[t] = bbase2[blockIdx.x * NEL + t];
    __syncthreads();
    int n = blockIdx.x * 256 + t;
    int p = atomicAdd(&cur[elem[n]], 1);
    order[p] = n;
}

// ---------------- sc1 lookup table: sc1tab[e] = W_embed[e] @ Wsc1[e] ----------------
__global__ __launch_bounds__(64) void k_sc1tab(const float* __restrict__ Wemb,
                                               const float* __restrict__ Wsc1,
                                               float* __restrict__ tab) {
    int e = blockIdx.x, d = threadIdx.x;
    float acc = 0.0f;
    for (int c = 0; c < 64; c++)
        acc += Wemb[e * 64 + c] * Wsc1[e * 4096 + c * 64 + d];
    tab[e * 64 + d] = acc;
}

// ---------------- CSR build over LIVE edges -----------------------------------------
__device__ __forceinline__ int edge_live(const float* pos, const float* shifts,
                                         const int* eidx, int e, int* rcv_out) {
    int snd = eidx[e];
    int rcv = eidx[EE + e];
    float vx = pos[rcv * 3 + 0] - pos[snd * 3 + 0] + shifts[e * 3 + 0];
    float vy = pos[rcv * 3 + 1] - pos[snd * 3 + 1] + shifts[e * 3 + 1];
    float vz = pos[rcv * 3 + 2] - pos[snd * 3 + 2] + shifts[e * 3 + 2];
    float r = sqrtf(vx * vx + vy * vy + vz * vz + 1e-12f);
    *rcv_out = rcv;
    return (r * 0.2f) < 1.0f;
}
__global__ __launch_bounds__(256) void k_csr_count(const float* __restrict__ pos,
                                                   const float* __restrict__ shifts,
                                                   const int* __restrict__ eidx,
                                                   int* __restrict__ rowcnt) {
    int e = blockIdx.x * 256 + threadIdx.x;
    int rcv;
    if (edge_live(pos, shifts, eidx, e, &rcv)) atomicAdd(&rowcnt[rcv], 1);
}
// scan rowcnt -> rowoff/rowcur ; bhist -> offs-equivalent + bbase2 + node2 block map
__global__ __launch_bounds__(1024) void k_scan(const int* __restrict__ rowcnt,
                                               int* __restrict__ rowoff,
                                               int* __restrict__ rowcur,
                                               const int* __restrict__ bhist,
                                               int* __restrict__ bbase2,
                                               int* __restrict__ belem,
                                               int* __restrict__ bbase,
                                               int* __restrict__ blim) {
    __shared__ int part[1024];
    int t = threadIdx.x;
    if (t < NBLK2) belem[t] = -1;
    int loc[8]; int s = 0;
    #pragma unroll
    for (int k = 0; k < 8; k++) { loc[k] = rowcnt[t * 8 + k]; s += loc[k]; }
    part[t] = s;
    __syncthreads();
    for (int d = 1; d < 1024; d <<= 1) {
        int v = (t >= d) ? part[t - d] : 0;
        __syncthreads();
        part[t] += v;
        __syncthreads();
    }
    int run = (t > 0) ? part[t - 1] : 0;
    #pragma unroll
    for (int k = 0; k < 8; k++) {
        rowoff[t * 8 + k] = run; rowcur[t * 8 + k] = run; run += loc[k];
    }
    if (t == 1023) rowoff[8192] = run;
    __syncthreads();
    if (t == 0) {
        int s2 = 0, b = 0;
        for (int e = 0; e < NEL; e++) {
            int c = 0;
            int run2 = s2;
            for (int b2 = 0; b2 < NHB; b2++) {
                bbase2[b2 * NEL + e] = run2;
                int v = bhist[b2 * NEL + e];
                run2 += v; c += v;
            }
            for (int q = 0; q < c; q += 16) {
                belem[b] = e;
                bbase[b] = s2 + q;
                blim[b] = s2 + ((q + 16 < c) ? (q + 16) : c);
                b++;
            }
            s2 += c;
        }
    }
}
__global__ __launch_bounds__(256) void k_csr_fill(const float* __restrict__ pos,
                                                  const float* __restrict__ shifts,
                                                  const int* __restrict__ eidx,
                                                  int* __restrict__ rowcur,
                                                  int* __restrict__ elist) {
    int e = blockIdx.x * 256 + threadIdx.x;
    int rcv;
    if (edge_live(pos, shifts, eidx, e, &rcv)) {
        int p = atomicAdd(&rowcur[rcv], 1);
        elist[p] = e;
    }
}

// ---------------- edge MLP over CSR-ordered LIVE edges ------------------------------
__global__ __launch_bounds__(256) void edge_mlp(
    const float* __restrict__ feats, const float* __restrict__ pos,
    const float* __restrict__ shifts, const int* __restrict__ eidx,
    const int* __restrict__ elist, const int* __restrict__ rowoff,
    const float* __restrict__ Wra, const float* __restrict__ Wrb,
    unsigned int* __restrict__ msg, float4* __restrict__ ue4)
{
    int nlive = rowoff[NN];
    int e_base = blockIdx.x * 64;
    if (e_base >= nlive) return;

    __shared__ float smem[13760];
    __shared__ int   sSnd[64];
    float* sWaT  = smem;
    float* sWbT  = smem + 512;
    float* sMsg  = smem;
    float* sRb   = smem + 8704;
    float* sHidT = smem + 9216;

    int tid = threadIdx.x;

    if (tid < 64) {
        int idx = e_base + tid;
        int ok = idx < nlive;
        int e = ok ? elist[idx] : elist[nlive - 1];
        int snd = eidx[e];
        int rcv = eidx[EE + e];
        float vx = pos[rcv * 3 + 0] - pos[snd * 3 + 0] + shifts[e * 3 + 0];
        float vy = pos[rcv * 3 + 1] - pos[snd * 3 + 1] + shifts[e * 3 + 1];
        float vz = pos[rcv * 3 + 2] - pos[snd * 3 + 2] + shifts[e * 3 + 2];
        float r = sqrtf(vx * vx + vy * vy + vz * vz + 1e-12f);
        float rinv = 1.0f / r;
        float x = r * 0.2f;
        float x2 = x * x, x4 = x2 * x2, x5 = x4 * x;
        float env = 1.0f - 21.0f * x5 + 35.0f * x5 * x - 15.0f * x5 * x2;
        float pref = ok ? 0.632455532033676f * rinv * env : 0.0f;
        float s1, c1;
        __sincosf(0.62831853071795865f * r, &s1, &c1);
        float k2c = 2.0f * c1;
        float sp = 0.0f, sn = s1;
        #pragma unroll
        for (int b = 0; b < 8; b++) {
            sRb[b * 64 + tid] = pref * sn;
            float t = k2c * sn - sp; sp = sn; sn = t;
        }
        if (ok) ue4[idx] = make_float4(vx * rinv, vy * rinv, vz * rinv, 0.0f);
        sSnd[tid] = snd;
    }
    for (int idx = tid; idx < 512; idx += 256) {
        int b = idx >> 6, j = idx & 63;
        sWaT[j * 8 + b] = Wra[idx];
    }
    for (int idx = tid; idx < 64 * 128; idx += 256) {
        int j = idx >> 7, c = idx & 127;
        float v = Wrb[j * 256 + c] * (c < 64 ? 0.0625f : 0.10825317547305482f);
        int jb = j >> 2, jl = j & 3;
        int sj = ((jb ^ ((c >> 3) & 7)) << 2) | jl;
        sWbT[c * 64 + sj] = v;
    }
    __syncthreads();

    {
        int e = tid & 63, jg = tid >> 6;
        float rbv[8];
        #pragma unroll
        for (int b = 0; b < 8; b++) rbv[b] = sRb[b * 64 + e];
        const float4* waT4 = (const float4*)sWaT;
        float hid[16];
        #pragma unroll
        for (int jj = 0; jj < 16; jj++) {
            int j = jg * 16 + jj;
            float4 wa0 = waT4[j * 2 + 0];
            float4 wa1 = waT4[j * 2 + 1];
            float acc = rbv[0] * wa0.x + rbv[1] * wa0.y + rbv[2] * wa0.z + rbv[3] * wa0.w
                      + rbv[4] * wa1.x + rbv[5] * wa1.y + rbv[6] * wa1.z + rbv[7] * wa1.w;
            hid[jj] = silu_f(acc);
        }
        float4* hidT4 = (float4*)sHidT;
        int hk = (e >> 1) & 7;
        #pragma unroll
        for (int q = 0; q < 4; q++) {
            int j4 = jg * 4 + q;
            hidT4[e * 17 + (j4 ^ hk)] =
                make_float4(hid[q * 4 + 0], hid[q * 4 + 1], hid[q * 4 + 2], hid[q * 4 + 3]);
        }
    }
    __syncthreads();

    int cg = tid & 15, eg = tid >> 4;
    int e0 = eg * 4, c0 = cg * 8, cgl = cg & 7;
    const float4* hidT4 = (const float4*)sHidT;
    const float4* wbT4  = (const float4*)sWbT;
    int hk0 = ((e0 + 0) >> 1) & 7, hk1 = ((e0 + 1) >> 1) & 7;
    int hk2 = ((e0 + 2) >> 1) & 7, hk3 = ((e0 + 3) >> 1) & 7;
    float acc[4][8];
    #pragma unroll
    for (int i = 0; i < 4; i++)
        #pragma unroll
        for (int cc = 0; cc < 8; cc++) acc[i][cc] = 0.0f;

    for (int jb = 0; jb < 16; ++jb) {
        float4 h0_ = hidT4[(e0 + 0) * 17 + (jb ^ hk0)];
        float4 h1_ = hidT4[(e0 + 1) * 17 + (jb ^ hk1)];
        float4 h2_ = hidT4[(e0 + 2) * 17 + (jb ^ hk2)];
        float4 h3_ = hidT4[(e0 + 3) * 17 + (jb ^ hk3)];
        int wj = jb ^ cgl;
        #pragma unroll
        for (int cc = 0; cc < 8; cc++) {
            float4 wb = wbT4[(c0 + cc) * 16 + wj];
            acc[0][cc] += DOT4(h0_, wb);
            acc[1][cc] += DOT4(h1_, wb);
            acc[2][cc] += DOT4(h2_, wb);
            acc[3][cc] += DOT4(h3_, wb);
        }
    }
    __syncthreads();

    {
        float4* msg4 = (float4*)sMsg;
        #pragma unroll
        for (int i = 0; i < 4; ++i) {
            int e = e0 + i, xk = e & 7;
            msg4[e * 33 + ((2 * cg + 0) ^ xk)] =
                make_float4(acc[i][0], acc[i][1], acc[i][2], acc[i][3]);
            msg4[e * 33 + ((2 * cg + 1) ^ xk)] =
                make_float4(acc[i][4], acc[i][5], acc[i][6], acc[i][7]);
        }
    }
    __syncthreads();

    {
        int q = tid >> 6, c = tid & 63;
        #pragma unroll 4
        for (int i = 0; i < 16; ++i) {
            int e = q * 16 + i;
            int idx = e_base + e;
            if (idx >= nlive) continue;
            int snd = sSnd[e];
            float f = feats[(size_t)snd * CC + c];
            int xk = e & 7;
            float w0 = sMsg[e * 132 + (((c >> 2) ^ xk) << 2) + (c & 3)];
            float w1 = sMsg[e * 132 + (((16 + (c >> 2)) ^ xk) << 2) + (c & 3)];
            __half2 h = __floats2half2_rn(w0 * f, w1 * f);
            msg[(size_t)idx * 64 + c] = *(unsigned int*)&h;
        }
    }
}

// ---------------- streaming CSR gather: msg -> dense A[n,4,64] ----------------------
__global__ __launch_bounds__(256) void k_gather(
    const int* __restrict__ rowoff,
    const unsigned int* __restrict__ msg, const float4* __restrict__ ue4,
    float* __restrict__ A)
{
    int n = blockIdx.x * 4 + (threadIdx.x >> 6);
    int d = threadIdx.x & 63;
    int s0 = rowoff[n], s1 = rowoff[n + 1];
    float a0 = 0.f, ax = 0.f, ay = 0.f, az = 0.f;
    for (int s = s0; s < s1; ++s) {
        unsigned int mu = msg[(size_t)s * 64 + d];
        float4 u = ue4[s];
        float2 m = __half22float2(*(__half2*)&mu);
        a0 += m.x;
        ax = fmaf(m.y, u.x, ax);
        ay = fmaf(m.y, u.y, ay);
        az = fmaf(m.y, u.z, az);
    }
    float* Ar = A + (size_t)n * 256;
    Ar[d] = a0; Ar[64 + d] = ax; Ar[128 + d] = ay; Ar[192 + d] = az;
}

// ---------------- node update 1: 8 nodes/block (2 per wave), 4 buffers, no restage --
__global__ __launch_bounds__(256) void node1(
    const int* __restrict__ elem, const float* __restrict__ A,
    const float* __restrict__ Wmix1, const float* __restrict__ sc1tab,
    const float* __restrict__ Wp1s, const float* __restrict__ Wp1v,
    const float* __restrict__ Wp10, const float* __restrict__ Wp11,
    const float* __restrict__ wrd1,
    float* __restrict__ out0, float* __restrict__ out1, float* __restrict__ d1)
{
    __shared__ float smem[18432];   // 72 KiB
    float* sW0 = smem;
    float* sW1 = smem + 4096;
    float* sP0 = smem + 8192;
    float* sP1 = smem + 12288;
    float* sIn = smem + 16384;      // 8 nodes x 4 rows x 64

    int tid = threadIdx.x, w = tid >> 6, d = tid & 63;
    stage_wT(Wmix1,        sW0, tid, 256);
    stage_wT(Wmix1 + 4096, sW1, tid, 256);
    stage_wT(Wp10,         sP0, tid, 256);
    stage_wT(Wp11,         sP1, tid, 256);
    int nbase = blockIdx.x * 8;
    for (int idx = tid; idx < 2048; idx += 256)
        sIn[idx] = A[(size_t)nbase * 256 + idx];
    __syncthreads();

    const float4* sIn4 = (const float4*)sIn;
    int rbase = w * 8;
    int nloc = nbase + w * 2;

    float accs[2] = {0.f, 0.f};
    float acch[2][3];
    #pragma unroll
    for (int i = 0; i < 2; i++) acch[i][0] = acch[i][1] = acch[i][2] = 0.f;

    for (int c4 = 0; c4 < 16; ++c4) {
        float4 w0 = WREAD(sW0, d, c4);
        float4 w1 = WREAD(sW1, d, c4);
        #pragma unroll
        for (int i = 0; i < 2; ++i) {
            int rb = rbase + i * 4;
            float4 a0 = sIn4[(rb + 0) * 16 + c4];
            accs[i] += DOT4(a0, w0);
            float4 a1 = sIn4[(rb + 1) * 16 + c4]; acch[i][0] += DOT4(a1, w1);
            float4 a2 = sIn4[(rb + 2) * 16 + c4]; acch[i][1] += DOT4(a2, w1);
            float4 a3 = sIn4[(rb + 3) * 16 + c4]; acch[i][2] += DOT4(a3, w1);
        }
    }

    #pragma unroll
    for (int i = 0; i < 2; ++i) {
        int n = nloc + i, e = elem[n];
        float s = accs[i];
        float ws0 = Wp1s[e * 64 + d], ws1 = Wp1s[640 + e * 64 + d], ws2 = Wp1s[1280 + e * 64 + d];
        float wv0 = Wp1v[e * 64 + d], wv1 = Wp1v[640 + e * 64 + d], wv2 = Wp1v[1280 + e * 64 + d];
        float m0 = s * (ws0 + s * (ws1 + s * ws2));
        float gv = wv0 + s * (wv1 + s * wv2);
        int rb = rbase + i * 4;
        sIn[(rb + 0) * 64 + d] = m0;
        sIn[(rb + 1) * 64 + d] = acch[i][0] * gv;
        sIn[(rb + 2) * 64 + d] = acch[i][1] * gv;
        sIn[(rb + 3) * 64 + d] = acch[i][2] * gv;
    }

    float acc0[2] = {0.f, 0.f};
    float acc1[2][3];
    #pragma unroll
    for (int i = 0; i < 2; i++) acc1[i][0] = acc1[i][1] = acc1[i][2] = 0.f;

    for (int c4 = 0; c4 < 16; ++c4) {
        float4 p0 = WREAD(sP0, d, c4);
        float4 p1 = WREAD(sP1, d, c4);
        #pragma unroll
        for (int i = 0; i < 2; ++i) {
            int rb = rbase + i * 4;
            float4 a0 = sIn4[(rb + 0) * 16 + c4];
            acc0[i] += DOT4(a0, p0);
            float4 a1 = sIn4[(rb + 1) * 16 + c4]; acc1[i][0] += DOT4(a1, p1);
            float4 a2 = sIn4[(rb + 2) * 16 + c4]; acc1[i][1] += DOT4(a2, p1);
            float4 a3 = sIn4[(rb + 3) * 16 + c4]; acc1[i][2] += DOT4(a3, p1);
        }
    }

    float wr = wrd1[d];
    #pragma unroll
    for (int i = 0; i < 2; ++i) {
        int n = nloc + i, e = elem[n];
        out0[(size_t)n * 64 + d] = acc0[i] + sc1tab[e * 64 + d];
        #pragma unroll
        for (int m = 0; m < 3; ++m) {
            float o = acc1[i][m];
            out1[((size_t)n * 3 + m) * 64 + d] = o;
            float v = o * wr;
            v += __shfl_xor(v, 32); v += __shfl_xor(v, 16); v += __shfl_xor(v, 8);
            v += __shfl_xor(v, 4);  v += __shfl_xor(v, 2);  v += __shfl_xor(v, 1);
            if (d == 0) d1[n * 3 + m] = v;
        }
    }
}

// ---------------- node update 2: flat block map, 512 thr; dip only (no atomics) ------
__global__ __launch_bounds__(512) void node2(
    const int* __restrict__ belem, const int* __restrict__ bbase,
    const int* __restrict__ blim, const int* __restrict__ order,
    const float* __restrict__ A, const float* __restrict__ out1,
    const float* __restrict__ d1,
    const float* __restrict__ Wmix2, const float* __restrict__ Wsc2,
    const float* __restrict__ Wpr2, const float* __restrict__ Wp2,
    const float* __restrict__ Wv, const float* __restrict__ Wg1,
    const float* __restrict__ bg1, const float* __restrict__ Wg2,
    const float* __restrict__ bg2, const float* __restrict__ wrd2,
    float* __restrict__ dip)
{
    int b = blockIdx.x;
    int e = belem[b];
    if (e < 0) return;
    int base = bbase[b];
    int nv = blim[b] - base;

    __shared__ float smem[13312];   // 52 KiB -> 3 blocks/CU
    __shared__ int   sNid[16];
    __shared__ int   sVal[16];
    float* sB0 = smem;
    float* sB1 = smem + 4096;
    float* sWv = smem + 8192;       // 1024 floats
    float* sIn = smem + 9216;       // 4096 floats

    int tid = threadIdx.x, w = tid >> 6, d = tid & 63;
    if (tid < 16) {
        sVal[tid] = tid < nv;
        sNid[tid] = order[base + (tid < nv ? tid : nv - 1)];
    }
    stage_wT(Wmix2,        sB0, tid, 512);
    stage_wT(Wmix2 + 4096, sB1, tid, 512);
    for (int idx = tid; idx < 1024; idx += 512) {
        int h = idx & 15, c = idx >> 4;
        sWv[(h << 6) + ((((c >> 2) ^ h) << 2) | (c & 3))] = Wv[idx];
    }
    __syncthreads();
    for (int idx = tid; idx < 4096; idx += 512) {
        int row = idx >> 6, q = row >> 2, k = row & 3, dd = idx & 63;
        sIn[idx] = A[(size_t)sNid[q] * 256 + k * 64 + dd];
    }
    __syncthreads();

    const float4* sIn4 = (const float4*)sIn;
    int rbase = w * 8;

    float accs[2] = {0.f, 0.f};
    float acch[2][3];
    #pragma unroll
    for (int i = 0; i < 2; i++) acch[i][0] = acch[i][1] = acch[i][2] = 0.f;

    for (int c4 = 0; c4 < 16; ++c4) {
        float4 w0 = WREAD(sB0, d, c4);
        float4 w1 = WREAD(sB1, d, c4);
        #pragma unroll
        for (int i = 0; i < 2; ++i) {
            int rb = rbase + i * 4;
            float4 a0 = sIn4[(rb + 0) * 16 + c4];
            accs[i] += DOT4(a0, w0);
            float4 a1 = sIn4[(rb + 1) * 16 + c4]; acch[i][0] += DOT4(a1, w1);
            float4 a2 = sIn4[(rb + 2) * 16 + c4]; acch[i][1] += DOT4(a2, w1);
            float4 a3 = sIn4[(rb + 3) * 16 + c4]; acch[i][2] += DOT4(a3, w1);
        }
    }

    float wp0 = Wpr2[e * 64 + d], wp1 = Wpr2[640 + e * 64 + d], wp2_ = Wpr2[1280 + e * 64 + d];
    #pragma unroll
    for (int i = 0; i < 2; ++i) {
        float s2 = accs[i];
        float gv2 = wp0 + s2 * (wp1 + s2 * wp2_);
        int rb = rbase + i * 4;
        sIn[(rb + 1) * 64 + d] = acch[i][0] * gv2;
        sIn[(rb + 2) * 64 + d] = acch[i][1] * gv2;
        sIn[(rb + 3) * 64 + d] = acch[i][2] * gv2;
    }
    __syncthreads();

    stage_wT(Wp2,             sB0, tid, 512);
    stage_wT(Wsc2 + e * 4096, sB1, tid, 512);
    __syncthreads();

    float acc2[2][3];
    #pragma unroll
    for (int i = 0; i < 2; i++) acc2[i][0] = acc2[i][1] = acc2[i][2] = 0.f;
    const float4* o14 = (const float4*)out1;

    for (int c4 = 0; c4 < 16; ++c4) {
        float4 p = WREAD(sB0, d, c4);
        float4 s = WREAD(sB1, d, c4);
        #pragma unroll
        for (int i = 0; i < 2; ++i) {
            int rb = rbase + i * 4;
            size_t nq = (size_t)sNid[w * 2 + i];
            #pragma unroll
            for (int m = 0; m < 3; ++m) {
                float4 t  = sIn4[(rb + 1 + m) * 16 + c4];
                float4 o1 = o14[(nq * 3 + m) * 16 + c4];
                acc2[i][m] += DOT4(t, p) + DOT4(o1, s);
            }
        }
    }

    int m = d >> 4, h = d & 15;
    const float4* sWv4 = (const float4*)sWv;
    #pragma unroll
    for (int i = 0; i < 2; ++i) {
        int q = w * 2 + i, rb = rbase + i * 4;
        int n = sNid[q], valid = sVal[q];
        sIn[(rb + 1) * 64 + d] = acc2[i][0];
        sIn[(rb + 2) * 64 + d] = acc2[i][1];
        sIn[(rb + 3) * 64 + d] = acc2[i][2];

        float vh = 0.f;
        if (d < 48) {
            for (int c4 = 0; c4 < 16; ++c4) {
                float4 o2 = sIn4[(rb + 1 + m) * 16 + c4];
                float4 wv = sWv4[(h << 4) + (c4 ^ h)];
                vh += DOT4(o2, wv);
            }
            sIn[rb * 64 + m * 16 + h] = vh;
        }
        float* g = sIn + rb * 64;
        if (d < 16) {
            float v0 = g[d], v1 = g[16 + d], v2 = g[32 + d];
            g[48 + d] = sqrtf(v0 * v0 + v1 * v1 + v2 * v2 + 1e-12f);
        }
        if (d < 16) {
            float acc = bg1[d];
            for (int k = 0; k < 16; ++k) acc += g[48 + k] * Wg1[k * 16 + d];
            g[48 + d] = silu_f(acc);
        }
        if (d < 16) {
            float acc = bg2[d];
            for (int k = 0; k < 16; ++k) acc += g[48 + k] * Wg2[k * 16 + d];
            g[48 + d] = acc * wrd2[d];
        }
        if (d < 48) {
            float v = vh * g[48 + h];
            v += __shfl_xor(v, 8, 16); v += __shfl_xor(v, 4, 16);
            v += __shfl_xor(v, 2, 16); v += __shfl_xor(v, 1, 16);
            if (h == 0 && valid)
                dip[n * 3 + m] = d1[n * 3 + m] + v;
        }
    }
}

// ---------------- graph total: per-block partials (LDS) + fixed-order final ----------
__global__ __launch_bounds__(256) void k_total_part(
    const float* __restrict__ dip, const float* __restrict__ chg,
    const float* __restrict__ pos, const int* __restrict__ batch,
    float* __restrict__ wtotal)
{
    __shared__ float tot[GG * 3];
    int t = threadIdx.x;
    for (int i = t; i < GG * 3; i += 256) tot[i] = 0.f;
    __syncthreads();
    int n = blockIdx.x * 256 + t;
    int g = batch[n];
    float c = chg[n];
    atomicAdd(&tot[g * 3 + 0], dip[n * 3 + 0] + c * pos[n * 3 + 0]);
    atomicAdd(&tot[g * 3 + 1], dip[n * 3 + 1] + c * pos[n * 3 + 1]);
    atomicAdd(&tot[g * 3 + 2], dip[n * 3 + 2] + c * pos[n * 3 + 2]);
    __syncthreads();
    for (int i = t; i < GG * 3; i += 256) wtotal[blockIdx.x * (GG * 3) + i] = tot[i];
}
__global__ __launch_bounds__(96) void k_total_final(const float* __restrict__ wtotal,
                                                    float* __restrict__ total) {
    int i = threadIdx.x;
    float s = 0.f;
    for (int b = 0; b < NHB; b++) s += wtotal[b * (GG * 3) + i];
    total[i] = s;
}

extern "C" void kernel_launch(void* const* d_in, const int* in_sizes, int n_in,
                              void* d_out, int out_size, void* d_ws, size_t ws_size,
                              hipStream_t stream) {
    const float* na     = (const float*)d_in[0];
    const float* pos    = (const float*)d_in[1];
    const float* shifts = (const float*)d_in[2];
    const float* chg    = (const float*)d_in[3];
    const int*   eidx   = (const int*)d_in[4];
    const int*   batch  = (const int*)d_in[5];
    const float* Wemb   = (const float*)d_in[7];
    const float* Wr1a   = (const float*)d_in[8];
    const float* Wr1b   = (const float*)d_in[9];
    const float* Wmix1  = (const float*)d_in[10];
    const float* Wsc1   = (const float*)d_in[11];
    const float* Wp1s   = (const float*)d_in[12];
    const float* Wp1v   = (const float*)d_in[13];
    const float* Wp10   = (const float*)d_in[14];
    const float* Wp11   = (const float*)d_in[15];
    const float* wrd1   = (const float*)d_in[16];
    const float* Wr2a   = (const float*)d_in[17];
    const float* Wr2b   = (const float*)d_in[18];
    const float* Wmix2  = (const float*)d_in[19];
    const float* Wsc2   = (const float*)d_in[20];
    const float* Wpr2   = (const float*)d_in[21];
    const float* Wp2    = (const float*)d_in[22];
    const float* Wv     = (const float*)d_in[23];
    const float* Wg1    = (const float*)d_in[24];
    const float* bg1    = (const float*)d_in[25];
    const float* Wg2    = (const float*)d_in[26];
    const float* bg2    = (const float*)d_in[27];
    const float* wrd2   = (const float*)d_in[28];

    // ---- workspace layout -----------------------------------------------------------
    unsigned int* msg = (unsigned int*)d_ws;                  // EE*64 (half2)
    float4* ue4  = (float4*)(msg + (size_t)EE * 64);          // EE
    float* A     = (float*)(ue4 + EE);                        // N*4*C
    float* h0    = A + (size_t)NN * 4 * CC;                   // N*C
    float* out0  = h0 + (size_t)NN * CC;                      // N*C
    float* out1  = out0 + (size_t)NN * CC;                    // N*3*C
    float* d1    = out1 + (size_t)NN * 3 * CC;                // N*3
    float* sc1t  = d1 + (size_t)NN * 3;                       // NEL*64
    float* wtotal= sc1t + NEL * 64;                           // NHB*96
    int* elem    = (int*)(wtotal + NHB * GG * 3);             // N
    int* bhist   = elem + NN;                                 // NHB*NEL
    int* bbase2  = bhist + NHB * NEL;                         // NHB*NEL
    int* rowcnt  = bbase2 + NHB * NEL;                        // N
    int* rowoff  = rowcnt + NN;                               // N+1
    int* rowcur  = rowoff + NN + 1;                           // N
    int* order   = rowcur + NN;                               // N
    int* elist   = order + NN;                                // E
    int* belem   = elist + EE;                                // NBLK2
    int* bbase   = belem + NBLK2;                             // NBLK2
    int* blim    = bbase + NBLK2;                             // NBLK2

    float* total = (float*)d_out;                             // G*3
    float* dip   = total + GG * 3;                            // N*3

    hipMemsetAsync(rowcnt, 0, (size_t)NN * sizeof(int), stream);

    k_h0<<<NN / 4, 256, 0, stream>>>(na, Wemb, h0, elem);
    k_csr_count<<<EE / 256, 256, 0, stream>>>(pos, shifts, eidx, rowcnt);
    k_hist<<<NHB, 256, 0, stream>>>(elem, bhist);
    k_scan<<<1, 1024, 0, stream>>>(rowcnt, rowoff, rowcur, bhist, bbase2,
                                   belem, bbase, blim);
    k_csr_fill<<<EE / 256, 256, 0, stream>>>(pos, shifts, eidx, rowcur, elist);
    k_fill<<<NHB, 256, 0, stream>>>(elem, bbase2, order);
    k_sc1tab<<<NEL, 64, 0, stream>>>(Wemb, Wsc1, sc1t);

    edge_mlp<<<EE / 64, 256, 0, stream>>>(h0, pos, shifts, eidx, elist, rowoff,
                                          Wr1a, Wr1b, msg, ue4);
    k_gather<<<NN / 4, 256, 0, stream>>>(rowoff, msg, ue4, A);
    node1<<<NN / 8, 256, 0, stream>>>(elem, A, Wmix1, sc1t, Wp1s, Wp1v, Wp10, Wp11,
                                      wrd1, out0, out1, d1);
    edge_mlp<<<EE / 64, 256, 0, stream>>>(out0, pos, shifts, eidx, elist, rowoff,
                                          Wr2a, Wr2b, msg, ue4);
    k_gather<<<NN / 4, 256, 0, stream>>>(rowoff, msg, ue4, A);
    node2<<<NBLK2, 512, 0, stream>>>(belem, bbase, blim, order, A, out1, d1,
                                     Wmix2, Wsc2, Wpr2, Wp2, Wv, Wg1, bg1,
                                     Wg2, bg2, wrd2, dip);
    k_total_part<<<NHB, 256, 0, stream>>>(dip, chg, pos, batch, wtotal);
    k_total_final<<<1, 96, 0, stream>>>(wtotal, total);
}

// Round 11
// 256.096 us; speedup vs baseline: 1.8740x; 1.1040x over previous
//
#include <hip/hip_runtime.h>
#include <hip/hip_fp16.h>
#include <math.h>

#define NN 8192
#define EE 131072
#define CC 64
#define GG 32
#define NEL 10
#define NBLK2 522
#define NHB 32          // histogram blocks (NN/256)

__device__ __forceinline__ float silu_f(float x) { return x / (1.0f + __expf(-x)); }

// stage a 64x64 row-major matrix W[c][d] into LDS transposed+XOR-swizzled
__device__ __forceinline__ void stage_wT(const float* __restrict__ W, float* sWT,
                                         int tid, int nt) {
    for (int idx = tid; idx < 4096; idx += nt) {
        int d = idx & 63, c = idx >> 6;
        sWT[(d << 6) + ((((c >> 2) ^ (d & 15)) << 2) | (c & 3))] = W[idx];
    }
}
#define WREAD(sWT, d, c4) (((const float4*)(sWT))[((d) << 4) + ((c4) ^ ((d) & 15))])
#define DOT4(a, b) ((a).x * (b).x + (a).y * (b).y + (a).z * (b).z + (a).w * (b).w)

// ---------------- h0 = W_embed[elem] ; elem = argmax (no atomics) -------------------
__global__ __launch_bounds__(256) void k_h0(const float* __restrict__ na,
                                            const float* __restrict__ Wemb,
                                            float* __restrict__ h0,
                                            int* __restrict__ elem) {
    int n = blockIdx.x * 4 + (threadIdx.x >> 6);
    int d = threadIdx.x & 63;
    float acc = 0.0f;
    float best = -1.0f; int bi = 0;
    #pragma unroll
    for (int k = 0; k < NEL; k++) {
        float a = na[n * NEL + k];
        acc += a * Wemb[k * 64 + d];
        if (a > best) { best = a; bi = k; }
    }
    h0[n * 64 + d] = acc;
    if (d == 0) elem[n] = bi;
}

// ---------------- per-block element histogram (LDS atomics only) --------------------
__global__ __launch_bounds__(256) void k_hist(const int* __restrict__ elem,
                                              int* __restrict__ bhist) {
    __shared__ int h[NEL];
    int t = threadIdx.x;
    if (t < NEL) h[t] = 0;
    __syncthreads();
    atomicAdd(&h[elem[blockIdx.x * 256 + t]], 1);
    __syncthreads();
    if (t < NEL) bhist[blockIdx.x * NEL + t] = h[t];
}

// ---------------- counting-sort fill (LDS cursors, no global contention) ------------
__global__ __launch_bounds__(256) void k_fill(const int* __restrict__ elem,
                                              const int* __restrict__ bbase2,
                                              int* __restrict__ order) {
    __shared__ int cur[NEL];
    int t = threadIdx.x;
    if (t < NEL) cur[t] = bbase2[blockIdx.x * NEL + t];
    __syncthreads();
    int n = blockIdx.x * 256 + t;
    int p = atomicAdd(&cur[elem[n]], 1);
    order[p] = n;
}

// ---------------- sc1 lookup table: sc1tab[e] = W_embed[e] @ Wsc1[e] ----------------
__global__ __launch_bounds__(64) void k_sc1tab(const float* __restrict__ Wemb,
                                               const float* __restrict__ Wsc1,
                                               float* __restrict__ tab) {
    int e = blockIdx.x, d = threadIdx.x;
    float acc = 0.0f;
    for (int c = 0; c < 64; c++)
        acc += Wemb[e * 64 + c] * Wsc1[e * 4096 + c * 64 + d];
    tab[e * 64 + d] = acc;
}

// ---------------- CSR build over LIVE edges -----------------------------------------
__device__ __forceinline__ int edge_live(const float* pos, const float* shifts,
                                         const int* eidx, int e, int* rcv_out) {
    int snd = eidx[e];
    int rcv = eidx[EE + e];
    float vx = pos[rcv * 3 + 0] - pos[snd * 3 + 0] + shifts[e * 3 + 0];
    float vy = pos[rcv * 3 + 1] - pos[snd * 3 + 1] + shifts[e * 3 + 1];
    float vz = pos[rcv * 3 + 2] - pos[snd * 3 + 2] + shifts[e * 3 + 2];
    float r = sqrtf(vx * vx + vy * vy + vz * vz + 1e-12f);
    *rcv_out = rcv;
    return (r * 0.2f) < 1.0f;
}
__global__ __launch_bounds__(256) void k_csr_count(const float* __restrict__ pos,
                                                   const float* __restrict__ shifts,
                                                   const int* __restrict__ eidx,
                                                   int* __restrict__ rowcnt) {
    int e = blockIdx.x * 256 + threadIdx.x;
    int rcv;
    if (edge_live(pos, shifts, eidx, e, &rcv)) atomicAdd(&rowcnt[rcv], 1);
}
// scan rowcnt -> rowoff/rowcur ; bhist -> bbase2 + node2 block map
__global__ __launch_bounds__(1024) void k_scan(const int* __restrict__ rowcnt,
                                               int* __restrict__ rowoff,
                                               int* __restrict__ rowcur,
                                               const int* __restrict__ bhist,
                                               int* __restrict__ bbase2,
                                               int* __restrict__ belem,
                                               int* __restrict__ bbase,
                                               int* __restrict__ blim) {
    __shared__ int part[1024];
    int t = threadIdx.x;
    if (t < NBLK2) belem[t] = -1;
    int loc[8]; int s = 0;
    #pragma unroll
    for (int k = 0; k < 8; k++) { loc[k] = rowcnt[t * 8 + k]; s += loc[k]; }
    part[t] = s;
    __syncthreads();
    for (int d = 1; d < 1024; d <<= 1) {
        int v = (t >= d) ? part[t - d] : 0;
        __syncthreads();
        part[t] += v;
        __syncthreads();
    }
    int run = (t > 0) ? part[t - 1] : 0;
    #pragma unroll
    for (int k = 0; k < 8; k++) {
        rowoff[t * 8 + k] = run; rowcur[t * 8 + k] = run; run += loc[k];
    }
    if (t == 1023) rowoff[8192] = run;
    __syncthreads();
    if (t == 0) {
        int s2 = 0, b = 0;
        for (int e = 0; e < NEL; e++) {
            int c = 0;
            int run2 = s2;
            for (int b2 = 0; b2 < NHB; b2++) {
                bbase2[b2 * NEL + e] = run2;
                int v = bhist[b2 * NEL + e];
                run2 += v; c += v;
            }
            for (int q = 0; q < c; q += 16) {
                belem[b] = e;
                bbase[b] = s2 + q;
                blim[b] = s2 + ((q + 16 < c) ? (q + 16) : c);
                b++;
            }
            s2 += c;
        }
    }
}
__global__ __launch_bounds__(256) void k_csr_fill(const float* __restrict__ pos,
                                                  const float* __restrict__ shifts,
                                                  const int* __restrict__ eidx,
                                                  int* __restrict__ rowcur,
                                                  int* __restrict__ elist) {
    int e = blockIdx.x * 256 + threadIdx.x;
    int rcv;
    if (edge_live(pos, shifts, eidx, e, &rcv)) {
        int p = atomicAdd(&rowcur[rcv], 1);
        elist[p] = e;
    }
}

// ---------------- edge MLP over CSR-ordered LIVE edges ------------------------------
__global__ __launch_bounds__(256) void edge_mlp(
    const float* __restrict__ feats, const float* __restrict__ pos,
    const float* __restrict__ shifts, const int* __restrict__ eidx,
    const int* __restrict__ elist, const int* __restrict__ rowoff,
    const float* __restrict__ Wra, const float* __restrict__ Wrb,
    unsigned int* __restrict__ msg, float4* __restrict__ ue4)
{
    int nlive = rowoff[NN];
    int e_base = blockIdx.x * 64;
    if (e_base >= nlive) return;

    __shared__ float smem[13760];
    __shared__ int   sSnd[64];
    float* sWaT  = smem;
    float* sWbT  = smem + 512;
    float* sMsg  = smem;
    float* sRb   = smem + 8704;
    float* sHidT = smem + 9216;

    int tid = threadIdx.x;

    if (tid < 64) {
        int idx = e_base + tid;
        int ok = idx < nlive;
        int e = ok ? elist[idx] : elist[nlive - 1];
        int snd = eidx[e];
        int rcv = eidx[EE + e];
        float vx = pos[rcv * 3 + 0] - pos[snd * 3 + 0] + shifts[e * 3 + 0];
        float vy = pos[rcv * 3 + 1] - pos[snd * 3 + 1] + shifts[e * 3 + 1];
        float vz = pos[rcv * 3 + 2] - pos[snd * 3 + 2] + shifts[e * 3 + 2];
        float r = sqrtf(vx * vx + vy * vy + vz * vz + 1e-12f);
        float rinv = 1.0f / r;
        float x = r * 0.2f;
        float x2 = x * x, x4 = x2 * x2, x5 = x4 * x;
        float env = 1.0f - 21.0f * x5 + 35.0f * x5 * x - 15.0f * x5 * x2;
        float pref = ok ? 0.632455532033676f * rinv * env : 0.0f;
        float s1, c1;
        __sincosf(0.62831853071795865f * r, &s1, &c1);
        float k2c = 2.0f * c1;
        float sp = 0.0f, sn = s1;
        #pragma unroll
        for (int b = 0; b < 8; b++) {
            sRb[b * 64 + tid] = pref * sn;
            float t = k2c * sn - sp; sp = sn; sn = t;
        }
        if (ok) ue4[idx] = make_float4(vx * rinv, vy * rinv, vz * rinv, 0.0f);
        sSnd[tid] = snd;
    }
    for (int idx = tid; idx < 512; idx += 256) {
        int b = idx >> 6, j = idx & 63;
        sWaT[j * 8 + b] = Wra[idx];
    }
    for (int idx = tid; idx < 64 * 128; idx += 256) {
        int j = idx >> 7, c = idx & 127;
        float v = Wrb[j * 256 + c] * (c < 64 ? 0.0625f : 0.10825317547305482f);
        int jb = j >> 2, jl = j & 3;
        int sj = ((jb ^ ((c >> 3) & 7)) << 2) | jl;
        sWbT[c * 64 + sj] = v;
    }
    __syncthreads();

    {
        int e = tid & 63, jg = tid >> 6;
        float rbv[8];
        #pragma unroll
        for (int b = 0; b < 8; b++) rbv[b] = sRb[b * 64 + e];
        const float4* waT4 = (const float4*)sWaT;
        float hid[16];
        #pragma unroll
        for (int jj = 0; jj < 16; jj++) {
            int j = jg * 16 + jj;
            float4 wa0 = waT4[j * 2 + 0];
            float4 wa1 = waT4[j * 2 + 1];
            float acc = rbv[0] * wa0.x + rbv[1] * wa0.y + rbv[2] * wa0.z + rbv[3] * wa0.w
                      + rbv[4] * wa1.x + rbv[5] * wa1.y + rbv[6] * wa1.z + rbv[7] * wa1.w;
            hid[jj] = silu_f(acc);
        }
        float4* hidT4 = (float4*)sHidT;
        int hk = (e >> 1) & 7;
        #pragma unroll
        for (int q = 0; q < 4; q++) {
            int j4 = jg * 4 + q;
            hidT4[e * 17 + (j4 ^ hk)] =
                make_float4(hid[q * 4 + 0], hid[q * 4 + 1], hid[q * 4 + 2], hid[q * 4 + 3]);
        }
    }
    __syncthreads();

    int cg = tid & 15, eg = tid >> 4;
    int e0 = eg * 4, c0 = cg * 8, cgl = cg & 7;
    const float4* hidT4 = (const float4*)sHidT;
    const float4* wbT4  = (const float4*)sWbT;
    int hk0 = ((e0 + 0) >> 1) & 7, hk1 = ((e0 + 1) >> 1) & 7;
    int hk2 = ((e0 + 2) >> 1) & 7, hk3 = ((e0 + 3) >> 1) & 7;
    float acc[4][8];
    #pragma unroll
    for (int i = 0; i < 4; i++)
        #pragma unroll
        for (int cc = 0; cc < 8; cc++) acc[i][cc] = 0.0f;

    for (int jb = 0; jb < 16; ++jb) {
        float4 h0_ = hidT4[(e0 + 0) * 17 + (jb ^ hk0)];
        float4 h1_ = hidT4[(e0 + 1) * 17 + (jb ^ hk1)];
        float4 h2_ = hidT4[(e0 + 2) * 17 + (jb ^ hk2)];
        float4 h3_ = hidT4[(e0 + 3) * 17 + (jb ^ hk3)];
        int wj = jb ^ cgl;
        #pragma unroll
        for (int cc = 0; cc < 8; cc++) {
            float4 wb = wbT4[(c0 + cc) * 16 + wj];
            acc[0][cc] += DOT4(h0_, wb);
            acc[1][cc] += DOT4(h1_, wb);
            acc[2][cc] += DOT4(h2_, wb);
            acc[3][cc] += DOT4(h3_, wb);
        }
    }
    __syncthreads();

    {
        float4* msg4 = (float4*)sMsg;
        #pragma unroll
        for (int i = 0; i < 4; ++i) {
            int e = e0 + i, xk = e & 7;
            msg4[e * 33 + ((2 * cg + 0) ^ xk)] =
                make_float4(acc[i][0], acc[i][1], acc[i][2], acc[i][3]);
            msg4[e * 33 + ((2 * cg + 1) ^ xk)] =
                make_float4(acc[i][4], acc[i][5], acc[i][6], acc[i][7]);
        }
    }
    __syncthreads();

    {
        int q = tid >> 6, c = tid & 63;
        #pragma unroll 4
        for (int i = 0; i < 16; ++i) {
            int e = q * 16 + i;
            int idx = e_base + e;
            if (idx >= nlive) continue;
            int snd = sSnd[e];
            float f = feats[(size_t)snd * CC + c];
            int xk = e & 7;
            float w0 = sMsg[e * 132 + (((c >> 2) ^ xk) << 2) + (c & 3)];
            float w1 = sMsg[e * 132 + (((16 + (c >> 2)) ^ xk) << 2) + (c & 3)];
            __half2 h = __floats2half2_rn(w0 * f, w1 * f);
            msg[(size_t)idx * 64 + c] = *(unsigned int*)&h;
        }
    }
}

// ---------------- streaming CSR gather: msg -> dense A[n,4,64] ----------------------
__global__ __launch_bounds__(256) void k_gather(
    const int* __restrict__ rowoff,
    const unsigned int* __restrict__ msg, const float4* __restrict__ ue4,
    float* __restrict__ A)
{
    int n = blockIdx.x * 4 + (threadIdx.x >> 6);
    int d = threadIdx.x & 63;
    int s0 = rowoff[n], s1 = rowoff[n + 1];
    float a0 = 0.f, ax = 0.f, ay = 0.f, az = 0.f;
    for (int s = s0; s < s1; ++s) {
        unsigned int mu = msg[(size_t)s * 64 + d];
        float4 u = ue4[s];
        float2 m = __half22float2(*(__half2*)&mu);
        a0 += m.x;
        ax = fmaf(m.y, u.x, ax);
        ay = fmaf(m.y, u.y, ay);
        az = fmaf(m.y, u.z, az);
    }
    float* Ar = A + (size_t)n * 256;
    Ar[d] = a0; Ar[64 + d] = ax; Ar[128 + d] = ay; Ar[192 + d] = az;
}

// ---------------- node update 1: 8 nodes/block, 40 KiB LDS, restage, unroll-capped --
__global__ __launch_bounds__(256) void node1(
    const int* __restrict__ elem, const float* __restrict__ A,
    const float* __restrict__ Wmix1, const float* __restrict__ sc1tab,
    const float* __restrict__ Wp1s, const float* __restrict__ Wp1v,
    const float* __restrict__ Wp10, const float* __restrict__ Wp11,
    const float* __restrict__ wrd1,
    float* __restrict__ out0, float* __restrict__ out1, float* __restrict__ d1)
{
    __shared__ float smem[10240];   // 40 KiB -> 4 blocks/CU
    float* sB0 = smem;
    float* sB1 = smem + 4096;
    float* sIn = smem + 8192;       // 8 nodes x 4 rows x 64

    int tid = threadIdx.x, w = tid >> 6, d = tid & 63;
    stage_wT(Wmix1,        sB0, tid, 256);
    stage_wT(Wmix1 + 4096, sB1, tid, 256);
    int nbase = blockIdx.x * 8;
    for (int idx = tid; idx < 2048; idx += 256)
        sIn[idx] = A[(size_t)nbase * 256 + idx];
    __syncthreads();

    const float4* sIn4 = (const float4*)sIn;
    int rbase = w * 8;
    int nloc = nbase + w * 2;

    float accs[2] = {0.f, 0.f};
    float acch[2][3];
    #pragma unroll
    for (int i = 0; i < 2; i++) acch[i][0] = acch[i][1] = acch[i][2] = 0.f;

    #pragma unroll 4
    for (int c4 = 0; c4 < 16; ++c4) {
        float4 w0 = WREAD(sB0, d, c4);
        float4 w1 = WREAD(sB1, d, c4);
        #pragma unroll
        for (int i = 0; i < 2; ++i) {
            int rb = rbase + i * 4;
            float4 a0 = sIn4[(rb + 0) * 16 + c4];
            accs[i] += DOT4(a0, w0);
            float4 a1 = sIn4[(rb + 1) * 16 + c4]; acch[i][0] += DOT4(a1, w1);
            float4 a2 = sIn4[(rb + 2) * 16 + c4]; acch[i][1] += DOT4(a2, w1);
            float4 a3 = sIn4[(rb + 3) * 16 + c4]; acch[i][2] += DOT4(a3, w1);
        }
    }

    #pragma unroll
    for (int i = 0; i < 2; ++i) {
        int n = nloc + i, e = elem[n];
        float s = accs[i];
        float ws0 = Wp1s[e * 64 + d], ws1 = Wp1s[640 + e * 64 + d], ws2 = Wp1s[1280 + e * 64 + d];
        float wv0 = Wp1v[e * 64 + d], wv1 = Wp1v[640 + e * 64 + d], wv2 = Wp1v[1280 + e * 64 + d];
        float m0 = s * (ws0 + s * (ws1 + s * ws2));
        float gv = wv0 + s * (wv1 + s * wv2);
        int rb = rbase + i * 4;
        sIn[(rb + 0) * 64 + d] = m0;
        sIn[(rb + 1) * 64 + d] = acch[i][0] * gv;
        sIn[(rb + 2) * 64 + d] = acch[i][1] * gv;
        sIn[(rb + 3) * 64 + d] = acch[i][2] * gv;
    }
    __syncthreads();                // all waves done reading sB0/sB1

    stage_wT(Wp10, sB0, tid, 256);
    stage_wT(Wp11, sB1, tid, 256);
    __syncthreads();

    float acc0[2] = {0.f, 0.f};
    float acc1[2][3];
    #pragma unroll
    for (int i = 0; i < 2; i++) acc1[i][0] = acc1[i][1] = acc1[i][2] = 0.f;

    #pragma unroll 4
    for (int c4 = 0; c4 < 16; ++c4) {
        float4 p0 = WREAD(sB0, d, c4);
        float4 p1 = WREAD(sB1, d, c4);
        #pragma unroll
        for (int i = 0; i < 2; ++i) {
            int rb = rbase + i * 4;
            float4 a0 = sIn4[(rb + 0) * 16 + c4];
            acc0[i] += DOT4(a0, p0);
            float4 a1 = sIn4[(rb + 1) * 16 + c4]; acc1[i][0] += DOT4(a1, p1);
            float4 a2 = sIn4[(rb + 2) * 16 + c4]; acc1[i][1] += DOT4(a2, p1);
            float4 a3 = sIn4[(rb + 3) * 16 + c4]; acc1[i][2] += DOT4(a3, p1);
        }
    }

    float wr = wrd1[d];
    #pragma unroll
    for (int i = 0; i < 2; ++i) {
        int n = nloc + i, e = elem[n];
        out0[(size_t)n * 64 + d] = acc0[i] + sc1tab[e * 64 + d];
        #pragma unroll
        for (int m = 0; m < 3; ++m) {
            float o = acc1[i][m];
            out1[((size_t)n * 3 + m) * 64 + d] = o;
            float v = o * wr;
            v += __shfl_xor(v, 32); v += __shfl_xor(v, 16); v += __shfl_xor(v, 8);
            v += __shfl_xor(v, 4);  v += __shfl_xor(v, 2);  v += __shfl_xor(v, 1);
            if (d == 0) d1[n * 3 + m] = v;
        }
    }
}

// ---------------- node update 2: flat block map, 512 thr; dip only (no atomics) ------
__global__ __launch_bounds__(512) void node2(
    const int* __restrict__ belem, const int* __restrict__ bbase,
    const int* __restrict__ blim, const int* __restrict__ order,
    const float* __restrict__ A, const float* __restrict__ out1,
    const float* __restrict__ d1,
    const float* __restrict__ Wmix2, const float* __restrict__ Wsc2,
    const float* __restrict__ Wpr2, const float* __restrict__ Wp2,
    const float* __restrict__ Wv, const float* __restrict__ Wg1,
    const float* __restrict__ bg1, const float* __restrict__ Wg2,
    const float* __restrict__ bg2, const float* __restrict__ wrd2,
    float* __restrict__ dip)
{
    int b = blockIdx.x;
    int e = belem[b];
    if (e < 0) return;
    int base = bbase[b];
    int nv = blim[b] - base;

    __shared__ float smem[13312];   // 52 KiB -> 3 blocks/CU
    __shared__ int   sNid[16];
    __shared__ int   sVal[16];
    float* sB0 = smem;
    float* sB1 = smem + 4096;
    float* sWv = smem + 8192;       // 1024 floats
    float* sIn = smem + 9216;       // 4096 floats

    int tid = threadIdx.x, w = tid >> 6, d = tid & 63;
    if (tid < 16) {
        sVal[tid] = tid < nv;
        sNid[tid] = order[base + (tid < nv ? tid : nv - 1)];
    }
    stage_wT(Wmix2,        sB0, tid, 512);
    stage_wT(Wmix2 + 4096, sB1, tid, 512);
    for (int idx = tid; idx < 1024; idx += 512) {
        int h = idx & 15, c = idx >> 4;
        sWv[(h << 6) + ((((c >> 2) ^ h) << 2) | (c & 3))] = Wv[idx];
    }
    __syncthreads();
    for (int idx = tid; idx < 4096; idx += 512) {
        int row = idx >> 6, q = row >> 2, k = row & 3, dd = idx & 63;
        sIn[idx] = A[(size_t)sNid[q] * 256 + k * 64 + dd];
    }
    __syncthreads();

    const float4* sIn4 = (const float4*)sIn;
    int rbase = w * 8;

    float accs[2] = {0.f, 0.f};
    float acch[2][3];
    #pragma unroll
    for (int i = 0; i < 2; i++) acch[i][0] = acch[i][1] = acch[i][2] = 0.f;

    #pragma unroll 4
    for (int c4 = 0; c4 < 16; ++c4) {
        float4 w0 = WREAD(sB0, d, c4);
        float4 w1 = WREAD(sB1, d, c4);
        #pragma unroll
        for (int i = 0; i < 2; ++i) {
            int rb = rbase + i * 4;
            float4 a0 = sIn4[(rb + 0) * 16 + c4];
            accs[i] += DOT4(a0, w0);
            float4 a1 = sIn4[(rb + 1) * 16 + c4]; acch[i][0] += DOT4(a1, w1);
            float4 a2 = sIn4[(rb + 2) * 16 + c4]; acch[i][1] += DOT4(a2, w1);
            float4 a3 = sIn4[(rb + 3) * 16 + c4]; acch[i][2] += DOT4(a3, w1);
        }
    }

    float wp0 = Wpr2[e * 64 + d], wp1 = Wpr2[640 + e * 64 + d], wp2_ = Wpr2[1280 + e * 64 + d];
    #pragma unroll
    for (int i = 0; i < 2; ++i) {
        float s2 = accs[i];
        float gv2 = wp0 + s2 * (wp1 + s2 * wp2_);
        int rb = rbase + i * 4;
        sIn[(rb + 1) * 64 + d] = acch[i][0] * gv2;
        sIn[(rb + 2) * 64 + d] = acch[i][1] * gv2;
        sIn[(rb + 3) * 64 + d] = acch[i][2] * gv2;
    }
    __syncthreads();

    stage_wT(Wp2,             sB0, tid, 512);
    stage_wT(Wsc2 + e * 4096, sB1, tid, 512);
    __syncthreads();

    float acc2[2][3];
    #pragma unroll
    for (int i = 0; i < 2; i++) acc2[i][0] = acc2[i][1] = acc2[i][2] = 0.f;
    const float4* o14 = (const float4*)out1;

    #pragma unroll 4
    for (int c4 = 0; c4 < 16; ++c4) {
        float4 p = WREAD(sB0, d, c4);
        float4 s = WREAD(sB1, d, c4);
        #pragma unroll
        for (int i = 0; i < 2; ++i) {
            int rb = rbase + i * 4;
            size_t nq = (size_t)sNid[w * 2 + i];
            #pragma unroll
            for (int m = 0; m < 3; ++m) {
                float4 t  = sIn4[(rb + 1 + m) * 16 + c4];
                float4 o1 = o14[(nq * 3 + m) * 16 + c4];
                acc2[i][m] += DOT4(t, p) + DOT4(o1, s);
            }
        }
    }

    int m = d >> 4, h = d & 15;
    const float4* sWv4 = (const float4*)sWv;
    #pragma unroll
    for (int i = 0; i < 2; ++i) {
        int q = w * 2 + i, rb = rbase + i * 4;
        int n = sNid[q], valid = sVal[q];
        sIn[(rb + 1) * 64 + d] = acc2[i][0];
        sIn[(rb + 2) * 64 + d] = acc2[i][1];
        sIn[(rb + 3) * 64 + d] = acc2[i][2];

        float vh = 0.f;
        if (d < 48) {
            #pragma unroll 4
            for (int c4 = 0; c4 < 16; ++c4) {
                float4 o2 = sIn4[(rb + 1 + m) * 16 + c4];
                float4 wv = sWv4[(h << 4) + (c4 ^ h)];
                vh += DOT4(o2, wv);
            }
            sIn[rb * 64 + m * 16 + h] = vh;
        }
        float* g = sIn + rb * 64;
        if (d < 16) {
            float v0 = g[d], v1 = g[16 + d], v2 = g[32 + d];
            g[48 + d] = sqrtf(v0 * v0 + v1 * v1 + v2 * v2 + 1e-12f);
        }
        if (d < 16) {
            float acc = bg1[d];
            for (int k = 0; k < 16; ++k) acc += g[48 + k] * Wg1[k * 16 + d];
            g[48 + d] = silu_f(acc);
        }
        if (d < 16) {
            float acc = bg2[d];
            for (int k = 0; k < 16; ++k) acc += g[48 + k] * Wg2[k * 16 + d];
            g[48 + d] = acc * wrd2[d];
        }
        if (d < 48) {
            float v = vh * g[48 + h];
            v += __shfl_xor(v, 8, 16); v += __shfl_xor(v, 4, 16);
            v += __shfl_xor(v, 2, 16); v += __shfl_xor(v, 1, 16);
            if (h == 0 && valid)
                dip[n * 3 + m] = d1[n * 3 + m] + v;
        }
    }
}

// ---------------- graph total: per-block partials (LDS) + fixed-order final ----------
__global__ __launch_bounds__(256) void k_total_part(
    const float* __restrict__ dip, const float* __restrict__ chg,
    const float* __restrict__ pos, const int* __restrict__ batch,
    float* __restrict__ wtotal)
{
    __shared__ float tot[GG * 3];
    int t = threadIdx.x;
    for (int i = t; i < GG * 3; i += 256) tot[i] = 0.f;
    __syncthreads();
    int n = blockIdx.x * 256 + t;
    int g = batch[n];
    float c = chg[n];
    atomicAdd(&tot[g * 3 + 0], dip[n * 3 + 0] + c * pos[n * 3 + 0]);
    atomicAdd(&tot[g * 3 + 1], dip[n * 3 + 1] + c * pos[n * 3 + 1]);
    atomicAdd(&tot[g * 3 + 2], dip[n * 3 + 2] + c * pos[n * 3 + 2]);
    __syncthreads();
    for (int i = t; i < GG * 3; i += 256) wtotal[blockIdx.x * (GG * 3) + i] = tot[i];
}
__global__ __launch_bounds__(96) void k_total_final(const float* __restrict__ wtotal,
                                                    float* __restrict__ total) {
    int i = threadIdx.x;
    float s = 0.f;
    for (int b = 0; b < NHB; b++) s += wtotal[b * (GG * 3) + i];
    total[i] = s;
}

extern "C" void kernel_launch(void* const* d_in, const int* in_sizes, int n_in,
                              void* d_out, int out_size, void* d_ws, size_t ws_size,
                              hipStream_t stream) {
    const float* na     = (const float*)d_in[0];
    const float* pos    = (const float*)d_in[1];
    const float* shifts = (const float*)d_in[2];
    const float* chg    = (const float*)d_in[3];
    const int*   eidx   = (const int*)d_in[4];
    const int*   batch  = (const int*)d_in[5];
    const float* Wemb   = (const float*)d_in[7];
    const float* Wr1a   = (const float*)d_in[8];
    const float* Wr1b   = (const float*)d_in[9];
    const float* Wmix1  = (const float*)d_in[10];
    const float* Wsc1   = (const float*)d_in[11];
    const float* Wp1s   = (const float*)d_in[12];
    const float* Wp1v   = (const float*)d_in[13];
    const float* Wp10   = (const float*)d_in[14];
    const float* Wp11   = (const float*)d_in[15];
    const float* wrd1   = (const float*)d_in[16];
    const float* Wr2a   = (const float*)d_in[17];
    const float* Wr2b   = (const float*)d_in[18];
    const float* Wmix2  = (const float*)d_in[19];
    const float* Wsc2   = (const float*)d_in[20];
    const float* Wpr2   = (const float*)d_in[21];
    const float* Wp2    = (const float*)d_in[22];
    const float* Wv     = (const float*)d_in[23];
    const float* Wg1    = (const float*)d_in[24];
    const float* bg1    = (const float*)d_in[25];
    const float* Wg2    = (const float*)d_in[26];
    const float* bg2    = (const float*)d_in[27];
    const float* wrd2   = (const float*)d_in[28];

    // ---- workspace layout -----------------------------------------------------------
    unsigned int* msg = (unsigned int*)d_ws;                  // EE*64 (half2)
    float4* ue4  = (float4*)(msg + (size_t)EE * 64);          // EE
    float* A     = (float*)(ue4 + EE);                        // N*4*C
    float* h0    = A + (size_t)NN * 4 * CC;                   // N*C
    float* out0  = h0 + (size_t)NN * CC;                      // N*C
    float* out1  = out0 + (size_t)NN * CC;                    // N*3*C
    float* d1    = out1 + (size_t)NN * 3 * CC;                // N*3
    float* sc1t  = d1 + (size_t)NN * 3;                       // NEL*64
    float* wtotal= sc1t + NEL * 64;                           // NHB*96
    int* elem    = (int*)(wtotal + NHB * GG * 3);             // N
    int* bhist   = elem + NN;                                 // NHB*NEL
    int* bbase2  = bhist + NHB * NEL;                         // NHB*NEL
    int* rowcnt  = bbase2 + NHB * NEL;                        // N
    int* rowoff  = rowcnt + NN;                               // N+1
    int* rowcur  = rowoff + NN + 1;                           // N
    int* order   = rowcur + NN;                               // N
    int* elist   = order + NN;                                // E
    int* belem   = elist + EE;                                // NBLK2
    int* bbase   = belem + NBLK2;                             // NBLK2
    int* blim    = bbase + NBLK2;                             // NBLK2

    float* total = (float*)d_out;                             // G*3
    float* dip   = total + GG * 3;                            // N*3

    hipMemsetAsync(rowcnt, 0, (size_t)NN * sizeof(int), stream);

    k_h0<<<NN / 4, 256, 0, stream>>>(na, Wemb, h0, elem);
    k_csr_count<<<EE / 256, 256, 0, stream>>>(pos, shifts, eidx, rowcnt);
    k_hist<<<NHB, 256, 0, stream>>>(elem, bhist);
    k_scan<<<1, 1024, 0, stream>>>(rowcnt, rowoff, rowcur, bhist, bbase2,
                                   belem, bbase, blim);
    k_csr_fill<<<EE / 256, 256, 0, stream>>>(pos, shifts, eidx, rowcur, elist);
    k_fill<<<NHB, 256, 0, stream>>>(elem, bbase2, order);
    k_sc1tab<<<NEL, 64, 0, stream>>>(Wemb, Wsc1, sc1t);

    edge_mlp<<<EE / 64, 256, 0, stream>>>(h0, pos, shifts, eidx, elist, rowoff,
                                          Wr1a, Wr1b, msg, ue4);
    k_gather<<<NN / 4, 256, 0, stream>>>(rowoff, msg, ue4, A);
    node1<<<NN / 8, 256, 0, stream>>>(elem, A, Wmix1, sc1t, Wp1s, Wp1v, Wp10, Wp11,
                                      wrd1, out0, out1, d1);
    edge_mlp<<<EE / 64, 256, 0, stream>>>(out0, pos, shifts, eidx, elist, rowoff,
                                          Wr2a, Wr2b, msg, ue4);
    k_gather<<<NN / 4, 256, 0, stream>>>(rowoff, msg, ue4, A);
    node2<<<NBLK2, 512, 0, stream>>>(belem, bbase, blim, order, A, out1, d1,
                                     Wmix2, Wsc2, Wpr2, Wp2, Wv, Wg1, bg1,
                                     Wg2, bg2, wrd2, dip);
    k_total_part<<<NHB, 256, 0, stream>>>(dip, chg, pos, batch, wtotal);
    k_total_final<<<1, 96, 0, stream>>>(wtotal, total);
}

// Round 12
// 221.669 us; speedup vs baseline: 2.1651x; 1.1553x over previous
//
#include <hip/hip_runtime.h>
#include <hip/hip_fp16.h>
#include <math.h>

#define NN 8192
#define EE 131072
#define CC 64
#define GG 32
#define NEL 10
#define NBLK2 522
#define NHB 32          // histogram blocks (NN/256)

__device__ __forceinline__ float silu_f(float x) { return x / (1.0f + __expf(-x)); }

typedef _Float16 h2v __attribute__((ext_vector_type(2)));
__device__ __forceinline__ float fdot2_u(unsigned int a, unsigned int b, float c) {
    return __builtin_amdgcn_fdot2(__builtin_bit_cast(h2v, a),
                                  __builtin_bit_cast(h2v, b), c, false);
}
__device__ __forceinline__ unsigned int pack_h2(float a, float b) {
    __half2 h = __floats2half2_rn(a, b);
    return *(unsigned int*)&h;
}

// stage a 64x64 row-major matrix W[c][d] into LDS transposed+XOR-swizzled
__device__ __forceinline__ void stage_wT(const float* __restrict__ W, float* sWT,
                                         int tid, int nt) {
    for (int idx = tid; idx < 4096; idx += nt) {
        int d = idx & 63, c = idx >> 6;
        sWT[(d << 6) + ((((c >> 2) ^ (d & 15)) << 2) | (c & 3))] = W[idx];
    }
}
#define WREAD(sWT, d, c4) (((const float4*)(sWT))[((d) << 4) + ((c4) ^ ((d) & 15))])
#define DOT4(a, b) ((a).x * (b).x + (a).y * (b).y + (a).z * (b).z + (a).w * (b).w)

// ---------------- h0 = W_embed[elem] ; elem = argmax (no atomics) -------------------
__global__ __launch_bounds__(256) void k_h0(const float* __restrict__ na,
                                            const float* __restrict__ Wemb,
                                            float* __restrict__ h0,
                                            int* __restrict__ elem) {
    int n = blockIdx.x * 4 + (threadIdx.x >> 6);
    int d = threadIdx.x & 63;
    float acc = 0.0f;
    float best = -1.0f; int bi = 0;
    #pragma unroll
    for (int k = 0; k < NEL; k++) {
        float a = na[n * NEL + k];
        acc += a * Wemb[k * 64 + d];
        if (a > best) { best = a; bi = k; }
    }
    h0[n * 64 + d] = acc;
    if (d == 0) elem[n] = bi;
}

// ---------------- per-block element histogram (LDS atomics only) --------------------
__global__ __launch_bounds__(256) void k_hist(const int* __restrict__ elem,
                                              int* __restrict__ bhist) {
    __shared__ int h[NEL];
    int t = threadIdx.x;
    if (t < NEL) h[t] = 0;
    __syncthreads();
    atomicAdd(&h[elem[blockIdx.x * 256 + t]], 1);
    __syncthreads();
    if (t < NEL) bhist[blockIdx.x * NEL + t] = h[t];
}

// ---------------- counting-sort fill (LDS cursors, no global contention) ------------
__global__ __launch_bounds__(256) void k_fill(const int* __restrict__ elem,
                                              const int* __restrict__ bbase2,
                                              int* __restrict__ order) {
    __shared__ int cur[NEL];
    int t = threadIdx.x;
    if (t < NEL) cur[t] = bbase2[blockIdx.x * NEL + t];
    __syncthreads();
    int n = blockIdx.x * 256 + t;
    int p = atomicAdd(&cur[elem[n]], 1);
    order[p] = n;
}

// ---------------- sc1 lookup table: sc1tab[e] = W_embed[e] @ Wsc1[e] ----------------
__global__ __launch_bounds__(64) void k_sc1tab(const float* __restrict__ Wemb,
                                               const float* __restrict__ Wsc1,
                                               float* __restrict__ tab) {
    int e = blockIdx.x, d = threadIdx.x;
    float acc = 0.0f;
    for (int c = 0; c < 64; c++)
        acc += Wemb[e * 64 + c] * Wsc1[e * 4096 + c * 64 + d];
    tab[e * 64 + d] = acc;
}

// ---------------- CSR build over LIVE edges -----------------------------------------
__device__ __forceinline__ int edge_live(const float* pos, const float* shifts,
                                         const int* eidx, int e, int* rcv_out) {
    int snd = eidx[e];
    int rcv = eidx[EE + e];
    float vx = pos[rcv * 3 + 0] - pos[snd * 3 + 0] + shifts[e * 3 + 0];
    float vy = pos[rcv * 3 + 1] - pos[snd * 3 + 1] + shifts[e * 3 + 1];
    float vz = pos[rcv * 3 + 2] - pos[snd * 3 + 2] + shifts[e * 3 + 2];
    float r = sqrtf(vx * vx + vy * vy + vz * vz + 1e-12f);
    *rcv_out = rcv;
    return (r * 0.2f) < 1.0f;
}
__global__ __launch_bounds__(256) void k_csr_count(const float* __restrict__ pos,
                                                   const float* __restrict__ shifts,
                                                   const int* __restrict__ eidx,
                                                   int* __restrict__ rowcnt) {
    int e = blockIdx.x * 256 + threadIdx.x;
    int rcv;
    if (edge_live(pos, shifts, eidx, e, &rcv)) atomicAdd(&rowcnt[rcv], 1);
}
// scan rowcnt -> rowoff/rowcur ; bhist -> bbase2 + node2 block map
__global__ __launch_bounds__(1024) void k_scan(const int* __restrict__ rowcnt,
                                               int* __restrict__ rowoff,
                                               int* __restrict__ rowcur,
                                               const int* __restrict__ bhist,
                                               int* __restrict__ bbase2,
                                               int* __restrict__ belem,
                                               int* __restrict__ bbase,
                                               int* __restrict__ blim) {
    __shared__ int part[1024];
    int t = threadIdx.x;
    if (t < NBLK2) belem[t] = -1;
    int loc[8]; int s = 0;
    #pragma unroll
    for (int k = 0; k < 8; k++) { loc[k] = rowcnt[t * 8 + k]; s += loc[k]; }
    part[t] = s;
    __syncthreads();
    for (int d = 1; d < 1024; d <<= 1) {
        int v = (t >= d) ? part[t - d] : 0;
        __syncthreads();
        part[t] += v;
        __syncthreads();
    }
    int run = (t > 0) ? part[t - 1] : 0;
    #pragma unroll
    for (int k = 0; k < 8; k++) {
        rowoff[t * 8 + k] = run; rowcur[t * 8 + k] = run; run += loc[k];
    }
    if (t == 1023) rowoff[8192] = run;
    __syncthreads();
    if (t == 0) {
        int s2 = 0, b = 0;
        for (int e = 0; e < NEL; e++) {
            int c = 0;
            int run2 = s2;
            for (int b2 = 0; b2 < NHB; b2++) {
                bbase2[b2 * NEL + e] = run2;
                int v = bhist[b2 * NEL + e];
                run2 += v; c += v;
            }
            for (int q = 0; q < c; q += 16) {
                belem[b] = e;
                bbase[b] = s2 + q;
                blim[b] = s2 + ((q + 16 < c) ? (q + 16) : c);
                b++;
            }
            s2 += c;
        }
    }
}
__global__ __launch_bounds__(256) void k_csr_fill(const float* __restrict__ pos,
                                                  const float* __restrict__ shifts,
                                                  const int* __restrict__ eidx,
                                                  int* __restrict__ rowcur,
                                                  int* __restrict__ elist) {
    int e = blockIdx.x * 256 + threadIdx.x;
    int rcv;
    if (edge_live(pos, shifts, eidx, e, &rcv)) {
        int p = atomicAdd(&rowcur[rcv], 1);
        elist[p] = e;
    }
}

// ---------------- edge MLP over CSR-ordered LIVE edges (fp16 dot2 version) ----------
// LDS (floats): [0,4608) overlay { sWaT 512 | sWbT 4096 uints } / { sMsg 9216 half }
//               [4608,5120) sRb ; [5120,7424) sHidT 2304 uints (64 rows x 36)
__global__ __launch_bounds__(256) void edge_mlp(
    const float* __restrict__ feats, const float* __restrict__ pos,
    const float* __restrict__ shifts, const int* __restrict__ eidx,
    const int* __restrict__ elist, const int* __restrict__ rowoff,
    const float* __restrict__ Wra, const float* __restrict__ Wrb,
    unsigned int* __restrict__ msg, float4* __restrict__ ue4)
{
    int nlive = rowoff[NN];
    int e_base = blockIdx.x * 64;
    if (e_base >= nlive) return;

    __shared__ float smem[7424];
    __shared__ int   sSnd[64];
    float* sWaT = smem;
    unsigned int* sWbT = (unsigned int*)(smem + 512);
    __half* sMsgH = (__half*)smem;
    float* sRb = smem + 4608;
    unsigned int* sHidT = (unsigned int*)(smem + 5120);

    int tid = threadIdx.x;

    // ---- phase A: geometry + radial basis (wave 0) + weight staging (all) ---------
    if (tid < 64) {
        int idx = e_base + tid;
        int ok = idx < nlive;
        int e = ok ? elist[idx] : elist[nlive - 1];
        int snd = eidx[e];
        int rcv = eidx[EE + e];
        float vx = pos[rcv * 3 + 0] - pos[snd * 3 + 0] + shifts[e * 3 + 0];
        float vy = pos[rcv * 3 + 1] - pos[snd * 3 + 1] + shifts[e * 3 + 1];
        float vz = pos[rcv * 3 + 2] - pos[snd * 3 + 2] + shifts[e * 3 + 2];
        float r = sqrtf(vx * vx + vy * vy + vz * vz + 1e-12f);
        float rinv = 1.0f / r;
        float x = r * 0.2f;
        float x2 = x * x, x4 = x2 * x2, x5 = x4 * x;
        float env = 1.0f - 21.0f * x5 + 35.0f * x5 * x - 15.0f * x5 * x2;
        float pref = ok ? 0.632455532033676f * rinv * env : 0.0f;
        float s1, c1;
        __sincosf(0.62831853071795865f * r, &s1, &c1);
        float k2c = 2.0f * c1;
        float sp = 0.0f, sn = s1;
        #pragma unroll
        for (int b = 0; b < 8; b++) {
            sRb[b * 64 + tid] = pref * sn;
            float t = k2c * sn - sp; sp = sn; sn = t;
        }
        if (ok) ue4[idx] = make_float4(vx * rinv, vy * rinv, vz * rinv, 0.0f);
        sSnd[tid] = snd;
    }
    for (int idx = tid; idx < 512; idx += 256) {
        int b = idx >> 6, j = idx & 63;
        sWaT[j * 8 + b] = Wra[idx];
    }
    // stage Wb as half2 pairs (j2 = j/2), chunk-swizzled by (c>>3)&7
    for (int idx = tid; idx < 4096; idx += 256) {
        int c = idx & 127, j2 = idx >> 7;
        float s = (c < 64) ? 0.0625f : 0.10825317547305482f;
        float v0 = Wrb[(2 * j2) * 256 + c] * s;
        float v1 = Wrb[(2 * j2 + 1) * 256 + c] * s;
        int sj2 = (((j2 >> 2) ^ ((c >> 3) & 7)) << 2) | (j2 & 3);
        sWbT[c * 32 + sj2] = pack_h2(v0, v1);
    }
    __syncthreads();

    // ---- phase B: hidden layer; store hid as half2, rows of 36 uints ----------------
    {
        int e = tid & 63, jg = tid >> 6;
        float rbv[8];
        #pragma unroll
        for (int b = 0; b < 8; b++) rbv[b] = sRb[b * 64 + e];
        const float4* waT4 = (const float4*)sWaT;
        float hid[16];
        #pragma unroll
        for (int jj = 0; jj < 16; jj++) {
            int j = jg * 16 + jj;
            float4 wa0 = waT4[j * 2 + 0];
            float4 wa1 = waT4[j * 2 + 1];
            float acc = rbv[0] * wa0.x + rbv[1] * wa0.y + rbv[2] * wa0.z + rbv[3] * wa0.w
                      + rbv[4] * wa1.x + rbv[5] * wa1.y + rbv[6] * wa1.z + rbv[7] * wa1.w;
            hid[jj] = silu_f(acc);
        }
        uint4* hidT4 = (uint4*)sHidT;   // row stride 9 uint4
        uint4 u0, u1;
        u0.x = pack_h2(hid[0], hid[1]);  u0.y = pack_h2(hid[2], hid[3]);
        u0.z = pack_h2(hid[4], hid[5]);  u0.w = pack_h2(hid[6], hid[7]);
        u1.x = pack_h2(hid[8], hid[9]);  u1.y = pack_h2(hid[10], hid[11]);
        u1.z = pack_h2(hid[12], hid[13]); u1.w = pack_h2(hid[14], hid[15]);
        hidT4[e * 9 + jg * 2 + 0] = u0;
        hidT4[e * 9 + jg * 2 + 1] = u1;
    }
    __syncthreads();

    // ---- phase C: wrf = hid @ WbT via v_dot2_f32_f16, tile 4 edges x 8 cols ---------
    int cg = tid & 15, eg = tid >> 4;
    int e0 = eg * 4, c0 = cg * 8, cgl = cg & 7;
    const uint4* hidT4c = (const uint4*)sHidT;
    const uint4* wbT4 = (const uint4*)sWbT;   // row stride 8 uint4
    float acc[4][8];
    #pragma unroll
    for (int i = 0; i < 4; i++)
        #pragma unroll
        for (int cc = 0; cc < 8; cc++) acc[i][cc] = 0.0f;

    for (int jc = 0; jc < 8; ++jc) {
        uint4 h0_ = hidT4c[(e0 + 0) * 9 + jc];
        uint4 h1_ = hidT4c[(e0 + 1) * 9 + jc];
        uint4 h2_ = hidT4c[(e0 + 2) * 9 + jc];
        uint4 h3_ = hidT4c[(e0 + 3) * 9 + jc];
        int wj = jc ^ cgl;
        #pragma unroll
        for (int cc = 0; cc < 8; cc++) {
            uint4 b = wbT4[(c0 + cc) * 8 + wj];
            acc[0][cc] = fdot2_u(h0_.x, b.x, acc[0][cc]);
            acc[0][cc] = fdot2_u(h0_.y, b.y, acc[0][cc]);
            acc[0][cc] = fdot2_u(h0_.z, b.z, acc[0][cc]);
            acc[0][cc] = fdot2_u(h0_.w, b.w, acc[0][cc]);
            acc[1][cc] = fdot2_u(h1_.x, b.x, acc[1][cc]);
            acc[1][cc] = fdot2_u(h1_.y, b.y, acc[1][cc]);
            acc[1][cc] = fdot2_u(h1_.z, b.z, acc[1][cc]);
            acc[1][cc] = fdot2_u(h1_.w, b.w, acc[1][cc]);
            acc[2][cc] = fdot2_u(h2_.x, b.x, acc[2][cc]);
            acc[2][cc] = fdot2_u(h2_.y, b.y, acc[2][cc]);
            acc[2][cc] = fdot2_u(h2_.z, b.z, acc[2][cc]);
            acc[2][cc] = fdot2_u(h2_.w, b.w, acc[2][cc]);
            acc[3][cc] = fdot2_u(h3_.x, b.x, acc[3][cc]);
            acc[3][cc] = fdot2_u(h3_.y, b.y, acc[3][cc]);
            acc[3][cc] = fdot2_u(h3_.z, b.z, acc[3][cc]);
            acc[3][cc] = fdot2_u(h3_.w, b.w, acc[3][cc]);
        }
    }
    __syncthreads();   // all reads of sWbT done before sMsg overlay write

    // ---- phase T: transpose to sMsgH (half, row 144, chunk-XOR by e&15) -------------
    {
        uint4* msgT4 = (uint4*)sMsgH;   // row stride 18 uint4
        #pragma unroll
        for (int i = 0; i < 4; ++i) {
            int e = e0 + i;
            int chunk = cg ^ (e & 15);
            uint4 u;
            u.x = pack_h2(acc[i][0], acc[i][1]);
            u.y = pack_h2(acc[i][2], acc[i][3]);
            u.z = pack_h2(acc[i][4], acc[i][5]);
            u.w = pack_h2(acc[i][6], acc[i][7]);
            msgT4[e * 18 + chunk] = u;
        }
    }
    __syncthreads();

    // ---- phase S: coalesced half2 message store in CSR order ------------------------
    {
        int q = tid >> 6, c = tid & 63;
        #pragma unroll 4
        for (int i = 0; i < 16; ++i) {
            int e = q * 16 + i;
            int idx = e_base + e;
            if (idx >= nlive) continue;
            int snd = sSnd[e];
            float f = feats[(size_t)snd * CC + c];
            int xk = e & 15;
            float w0 = __half2float(sMsgH[e * 144 + ((((c >> 3)) ^ xk) << 3) + (c & 7)]);
            float w1 = __half2float(sMsgH[e * 144 + (((8 + (c >> 3)) ^ xk) << 3) + (c & 7)]);
            __half2 h = __floats2half2_rn(w0 * f, w1 * f);
            msg[(size_t)idx * 64 + c] = *(unsigned int*)&h;
        }
    }
}

// ---------------- streaming CSR gather: msg -> dense A[n,4,64] ----------------------
__global__ __launch_bounds__(256) void k_gather(
    const int* __restrict__ rowoff,
    const unsigned int* __restrict__ msg, const float4* __restrict__ ue4,
    float* __restrict__ A)
{
    int n = blockIdx.x * 4 + (threadIdx.x >> 6);
    int d = threadIdx.x & 63;
    int s0 = rowoff[n], s1 = rowoff[n + 1];
    float a0 = 0.f, ax = 0.f, ay = 0.f, az = 0.f;
    for (int s = s0; s < s1; ++s) {
        unsigned int mu = msg[(size_t)s * 64 + d];
        float4 u = ue4[s];
        float2 m = __half22float2(*(__half2*)&mu);
        a0 += m.x;
        ax = fmaf(m.y, u.x, ax);
        ay = fmaf(m.y, u.y, ay);
        az = fmaf(m.y, u.z, az);
    }
    float* Ar = A + (size_t)n * 256;
    Ar[d] = a0; Ar[64 + d] = ax; Ar[128 + d] = ay; Ar[192 + d] = az;
}

// ---------------- node update 1: 8 nodes/block, 40 KiB LDS, restage, unroll-capped --
__global__ __launch_bounds__(256) void node1(
    const int* __restrict__ elem, const float* __restrict__ A,
    const float* __restrict__ Wmix1, const float* __restrict__ sc1tab,
    const float* __restrict__ Wp1s, const float* __restrict__ Wp1v,
    const float* __restrict__ Wp10, const float* __restrict__ Wp11,
    const float* __restrict__ wrd1,
    float* __restrict__ out0, float* __restrict__ out1, float* __restrict__ d1)
{
    __shared__ float smem[10240];   // 40 KiB -> 4 blocks/CU
    float* sB0 = smem;
    float* sB1 = smem + 4096;
    float* sIn = smem + 8192;       // 8 nodes x 4 rows x 64

    int tid = threadIdx.x, w = tid >> 6, d = tid & 63;
    stage_wT(Wmix1,        sB0, tid, 256);
    stage_wT(Wmix1 + 4096, sB1, tid, 256);
    int nbase = blockIdx.x * 8;
    for (int idx = tid; idx < 2048; idx += 256)
        sIn[idx] = A[(size_t)nbase * 256 + idx];
    __syncthreads();

    const float4* sIn4 = (const float4*)sIn;
    int rbase = w * 8;
    int nloc = nbase + w * 2;

    float accs[2] = {0.f, 0.f};
    float acch[2][3];
    #pragma unroll
    for (int i = 0; i < 2; i++) acch[i][0] = acch[i][1] = acch[i][2] = 0.f;

    #pragma unroll 4
    for (int c4 = 0; c4 < 16; ++c4) {
        float4 w0 = WREAD(sB0, d, c4);
        float4 w1 = WREAD(sB1, d, c4);
        #pragma unroll
        for (int i = 0; i < 2; ++i) {
            int rb = rbase + i * 4;
            float4 a0 = sIn4[(rb + 0) * 16 + c4];
            accs[i] += DOT4(a0, w0);
            float4 a1 = sIn4[(rb + 1) * 16 + c4]; acch[i][0] += DOT4(a1, w1);
            float4 a2 = sIn4[(rb + 2) * 16 + c4]; acch[i][1] += DOT4(a2, w1);
            float4 a3 = sIn4[(rb + 3) * 16 + c4]; acch[i][2] += DOT4(a3, w1);
        }
    }

    #pragma unroll
    for (int i = 0; i < 2; ++i) {
        int n = nloc + i, e = elem[n];
        float s = accs[i];
        float ws0 = Wp1s[e * 64 + d], ws1 = Wp1s[640 + e * 64 + d], ws2 = Wp1s[1280 + e * 64 + d];
        float wv0 = Wp1v[e * 64 + d], wv1 = Wp1v[640 + e * 64 + d], wv2 = Wp1v[1280 + e * 64 + d];
        float m0 = s * (ws0 + s * (ws1 + s * ws2));
        float gv = wv0 + s * (wv1 + s * wv2);
        int rb = rbase + i * 4;
        sIn[(rb + 0) * 64 + d] = m0;
        sIn[(rb + 1) * 64 + d] = acch[i][0] * gv;
        sIn[(rb + 2) * 64 + d] = acch[i][1] * gv;
        sIn[(rb + 3) * 64 + d] = acch[i][2] * gv;
    }
    __syncthreads();                // all waves done reading sB0/sB1

    stage_wT(Wp10, sB0, tid, 256);
    stage_wT(Wp11, sB1, tid, 256);
    __syncthreads();

    float acc0[2] = {0.f, 0.f};
    float acc1[2][3];
    #pragma unroll
    for (int i = 0; i < 2; i++) acc1[i][0] = acc1[i][1] = acc1[i][2] = 0.f;

    #pragma unroll 4
    for (int c4 = 0; c4 < 16; ++c4) {
        float4 p0 = WREAD(sB0, d, c4);
        float4 p1 = WREAD(sB1, d, c4);
        #pragma unroll
        for (int i = 0; i < 2; ++i) {
            int rb = rbase + i * 4;
            float4 a0 = sIn4[(rb + 0) * 16 + c4];
            acc0[i] += DOT4(a0, p0);
            float4 a1 = sIn4[(rb + 1) * 16 + c4]; acc1[i][0] += DOT4(a1, p1);
            float4 a2 = sIn4[(rb + 2) * 16 + c4]; acc1[i][1] += DOT4(a2, p1);
            float4 a3 = sIn4[(rb + 3) * 16 + c4]; acc1[i][2] += DOT4(a3, p1);
        }
    }

    float wr = wrd1[d];
    #pragma unroll
    for (int i = 0; i < 2; ++i) {
        int n = nloc + i, e = elem[n];
        out0[(size_t)n * 64 + d] = acc0[i] + sc1tab[e * 64 + d];
        #pragma unroll
        for (int m = 0; m < 3; ++m) {
            float o = acc1[i][m];
            out1[((size_t)n * 3 + m) * 64 + d] = o;
            float v = o * wr;
            v += __shfl_xor(v, 32); v += __shfl_xor(v, 16); v += __shfl_xor(v, 8);
            v += __shfl_xor(v, 4);  v += __shfl_xor(v, 2);  v += __shfl_xor(v, 1);
            if (d == 0) d1[n * 3 + m] = v;
        }
    }
}

// ---------------- node update 2: flat block map, 512 thr; dip only (no atomics) ------
__global__ __launch_bounds__(512) void node2(
    const int* __restrict__ belem, const int* __restrict__ bbase,
    const int* __restrict__ blim, const int* __restrict__ order,
    const float* __restrict__ A, const float* __restrict__ out1,
    const float* __restrict__ d1,
    const float* __restrict__ Wmix2, const float* __restrict__ Wsc2,
    const float* __restrict__ Wpr2, const float* __restrict__ Wp2,
    const float* __restrict__ Wv, const float* __restrict__ Wg1,
    const float* __restrict__ bg1, const float* __restrict__ Wg2,
    const float* __restrict__ bg2, const float* __restrict__ wrd2,
    float* __restrict__ dip)
{
    int b = blockIdx.x;
    int e = belem[b];
    if (e < 0) return;
    int base = bbase[b];
    int nv = blim[b] - base;

    __shared__ float smem[13312];   // 52 KiB -> 3 blocks/CU
    __shared__ int   sNid[16];
    __shared__ int   sVal[16];
    float* sB0 = smem;
    float* sB1 = smem + 4096;
    float* sWv = smem + 8192;       // 1024 floats
    float* sIn = smem + 9216;       // 4096 floats

    int tid = threadIdx.x, w = tid >> 6, d = tid & 63;
    if (tid < 16) {
        sVal[tid] = tid < nv;
        sNid[tid] = order[base + (tid < nv ? tid : nv - 1)];
    }
    stage_wT(Wmix2,        sB0, tid, 512);
    stage_wT(Wmix2 + 4096, sB1, tid, 512);
    for (int idx = tid; idx < 1024; idx += 512) {
        int h = idx & 15, c = idx >> 4;
        sWv[(h << 6) + ((((c >> 2) ^ h) << 2) | (c & 3))] = Wv[idx];
    }
    __syncthreads();
    for (int idx = tid; idx < 4096; idx += 512) {
        int row = idx >> 6, q = row >> 2, k = row & 3, dd = idx & 63;
        sIn[idx] = A[(size_t)sNid[q] * 256 + k * 64 + dd];
    }
    __syncthreads();

    const float4* sIn4 = (const float4*)sIn;
    int rbase = w * 8;

    float accs[2] = {0.f, 0.f};
    float acch[2][3];
    #pragma unroll
    for (int i = 0; i < 2; i++) acch[i][0] = acch[i][1] = acch[i][2] = 0.f;

    #pragma unroll 4
    for (int c4 = 0; c4 < 16; ++c4) {
        float4 w0 = WREAD(sB0, d, c4);
        float4 w1 = WREAD(sB1, d, c4);
        #pragma unroll
        for (int i = 0; i < 2; ++i) {
            int rb = rbase + i * 4;
            float4 a0 = sIn4[(rb + 0) * 16 + c4];
            accs[i] += DOT4(a0, w0);
            float4 a1 = sIn4[(rb + 1) * 16 + c4]; acch[i][0] += DOT4(a1, w1);
            float4 a2 = sIn4[(rb + 2) * 16 + c4]; acch[i][1] += DOT4(a2, w1);
            float4 a3 = sIn4[(rb + 3) * 16 + c4]; acch[i][2] += DOT4(a3, w1);
        }
    }

    float wp0 = Wpr2[e * 64 + d], wp1 = Wpr2[640 + e * 64 + d], wp2_ = Wpr2[1280 + e * 64 + d];
    #pragma unroll
    for (int i = 0; i < 2; ++i) {
        float s2 = accs[i];
        float gv2 = wp0 + s2 * (wp1 + s2 * wp2_);
        int rb = rbase + i * 4;
        sIn[(rb + 1) * 64 + d] = acch[i][0] * gv2;
        sIn[(rb + 2) * 64 + d] = acch[i][1] * gv2;
        sIn[(rb + 3) * 64 + d] = acch[i][2] * gv2;
    }
    __syncthreads();

    stage_wT(Wp2,             sB0, tid, 512);
    stage_wT(Wsc2 + e * 4096, sB1, tid, 512);
    __syncthreads();

    float acc2[2][3];
    #pragma unroll
    for (int i = 0; i < 2; i++) acc2[i][0] = acc2[i][1] = acc2[i][2] = 0.f;
    const float4* o14 = (const float4*)out1;

    #pragma unroll 4
    for (int c4 = 0; c4 < 16; ++c4) {
        float4 p = WREAD(sB0, d, c4);
        float4 s = WREAD(sB1, d, c4);
        #pragma unroll
        for (int i = 0; i < 2; ++i) {
            int rb = rbase + i * 4;
            size_t nq = (size_t)sNid[w * 2 + i];
            #pragma unroll
            for (int m = 0; m < 3; ++m) {
                float4 t  = sIn4[(rb + 1 + m) * 16 + c4];
                float4 o1 = o14[(nq * 3 + m) * 16 + c4];
                acc2[i][m] += DOT4(t, p) + DOT4(o1, s);
            }
        }
    }

    int m = d >> 4, h = d & 15;
    const float4* sWv4 = (const float4*)sWv;
    #pragma unroll
    for (int i = 0; i < 2; ++i) {
        int q = w * 2 + i, rb = rbase + i * 4;
        int n = sNid[q], valid = sVal[q];
        sIn[(rb + 1) * 64 + d] = acc2[i][0];
        sIn[(rb + 2) * 64 + d] = acc2[i][1];
        sIn[(rb + 3) * 64 + d] = acc2[i][2];

        float vh = 0.f;
        if (d < 48) {
            #pragma unroll 4
            for (int c4 = 0; c4 < 16; ++c4) {
                float4 o2 = sIn4[(rb + 1 + m) * 16 + c4];
                float4 wv = sWv4[(h << 4) + (c4 ^ h)];
                vh += DOT4(o2, wv);
            }
            sIn[rb * 64 + m * 16 + h] = vh;
        }
        float* g = sIn + rb * 64;
        if (d < 16) {
            float v0 = g[d], v1 = g[16 + d], v2 = g[32 + d];
            g[48 + d] = sqrtf(v0 * v0 + v1 * v1 + v2 * v2 + 1e-12f);
        }
        if (d < 16) {
            float acc = bg1[d];
            for (int k = 0; k < 16; ++k) acc += g[48 + k] * Wg1[k * 16 + d];
            g[48 + d] = silu_f(acc);
        }
        if (d < 16) {
            float acc = bg2[d];
            for (int k = 0; k < 16; ++k) acc += g[48 + k] * Wg2[k * 16 + d];
            g[48 + d] = acc * wrd2[d];
        }
        if (d < 48) {
            float v = vh * g[48 + h];
            v += __shfl_xor(v, 8, 16); v += __shfl_xor(v, 4, 16);
            v += __shfl_xor(v, 2, 16); v += __shfl_xor(v, 1, 16);
            if (h == 0 && valid)
                dip[n * 3 + m] = d1[n * 3 + m] + v;
        }
    }
}

// ---------------- graph total: per-block partials (LDS) + fixed-order final ----------
__global__ __launch_bounds__(256) void k_total_part(
    const float* __restrict__ dip, const float* __restrict__ chg,
    const float* __restrict__ pos, const int* __restrict__ batch,
    float* __restrict__ wtotal)
{
    __shared__ float tot[GG * 3];
    int t = threadIdx.x;
    for (int i = t; i < GG * 3; i += 256) tot[i] = 0.f;
    __syncthreads();
    int n = blockIdx.x * 256 + t;
    int g = batch[n];
    float c = chg[n];
    atomicAdd(&tot[g * 3 + 0], dip[n * 3 + 0] + c * pos[n * 3 + 0]);
    atomicAdd(&tot[g * 3 + 1], dip[n * 3 + 1] + c * pos[n * 3 + 1]);
    atomicAdd(&tot[g * 3 + 2], dip[n * 3 + 2] + c * pos[n * 3 + 2]);
    __syncthreads();
    for (int i = t; i < GG * 3; i += 256) wtotal[blockIdx.x * (GG * 3) + i] = tot[i];
}
__global__ __launch_bounds__(96) void k_total_final(const float* __restrict__ wtotal,
                                                    float* __restrict__ total) {
    int i = threadIdx.x;
    float s = 0.f;
    for (int b = 0; b < NHB; b++) s += wtotal[b * (GG * 3) + i];
    total[i] = s;
}

extern "C" void kernel_launch(void* const* d_in, const int* in_sizes, int n_in,
                              void* d_out, int out_size, void* d_ws, size_t ws_size,
                              hipStream_t stream) {
    const float* na     = (const float*)d_in[0];
    const float* pos    = (const float*)d_in[1];
    const float* shifts = (const float*)d_in[2];
    const float* chg    = (const float*)d_in[3];
    const int*   eidx   = (const int*)d_in[4];
    const int*   batch  = (const int*)d_in[5];
    const float* Wemb   = (const float*)d_in[7];
    const float* Wr1a   = (const float*)d_in[8];
    const float* Wr1b   = (const float*)d_in[9];
    const float* Wmix1  = (const float*)d_in[10];
    const float* Wsc1   = (const float*)d_in[11];
    const float* Wp1s   = (const float*)d_in[12];
    const float* Wp1v   = (const float*)d_in[13];
    const float* Wp10   = (const float*)d_in[14];
    const float* Wp11   = (const float*)d_in[15];
    const float* wrd1   = (const float*)d_in[16];
    const float* Wr2a   = (const float*)d_in[17];
    const float* Wr2b   = (const float*)d_in[18];
    const float* Wmix2  = (const float*)d_in[19];
    const float* Wsc2   = (const float*)d_in[20];
    const float* Wpr2   = (const float*)d_in[21];
    const float* Wp2    = (const float*)d_in[22];
    const float* Wv     = (const float*)d_in[23];
    const float* Wg1    = (const float*)d_in[24];
    const float* bg1    = (const float*)d_in[25];
    const float* Wg2    = (const float*)d_in[26];
    const float* bg2    = (const float*)d_in[27];
    const float* wrd2   = (const float*)d_in[28];

    // ---- workspace layout -----------------------------------------------------------
    unsigned int* msg = (unsigned int*)d_ws;                  // EE*64 (half2)
    float4* ue4  = (float4*)(msg + (size_t)EE * 64);          // EE
    float* A     = (float*)(ue4 + EE);                        // N*4*C
    float* h0    = A + (size_t)NN * 4 * CC;                   // N*C
    float* out0  = h0 + (size_t)NN * CC;                      // N*C
    float* out1  = out0 + (size_t)NN * CC;                    // N*3*C
    float* d1    = out1 + (size_t)NN * 3 * CC;                // N*3
    float* sc1t  = d1 + (size_t)NN * 3;                       // NEL*64
    float* wtotal= sc1t + NEL * 64;                           // NHB*96
    int* elem    = (int*)(wtotal + NHB * GG * 3);             // N
    int* bhist   = elem + NN;                                 // NHB*NEL
    int* bbase2  = bhist + NHB * NEL;                         // NHB*NEL
    int* rowcnt  = bbase2 + NHB * NEL;                        // N
    int* rowoff  = rowcnt + NN;                               // N+1
    int* rowcur  = rowoff + NN + 1;                           // N
    int* order   = rowcur + NN;                               // N
    int* elist   = order + NN;                                // E
    int* belem   = elist + EE;                                // NBLK2
    int* bbase   = belem + NBLK2;                             // NBLK2
    int* blim    = bbase + NBLK2;                             // NBLK2

    float* total = (float*)d_out;                             // G*3
    float* dip   = total + GG * 3;                            // N*3

    hipMemsetAsync(rowcnt, 0, (size_t)NN * sizeof(int), stream);

    k_h0<<<NN / 4, 256, 0, stream>>>(na, Wemb, h0, elem);
    k_csr_count<<<EE / 256, 256, 0, stream>>>(pos, shifts, eidx, rowcnt);
    k_hist<<<NHB, 256, 0, stream>>>(elem, bhist);
    k_scan<<<1, 1024, 0, stream>>>(rowcnt, rowoff, rowcur, bhist, bbase2,
                                   belem, bbase, blim);
    k_csr_fill<<<EE / 256, 256, 0, stream>>>(pos, shifts, eidx, rowcur, elist);
    k_fill<<<NHB, 256, 0, stream>>>(elem, bbase2, order);
    k_sc1tab<<<NEL, 64, 0, stream>>>(Wemb, Wsc1, sc1t);

    edge_mlp<<<EE / 64, 256, 0, stream>>>(h0, pos, shifts, eidx, elist, rowoff,
                                          Wr1a, Wr1b, msg, ue4);
    k_gather<<<NN / 4, 256, 0, stream>>>(rowoff, msg, ue4, A);
    node1<<<NN / 8, 256, 0, stream>>>(elem, A, Wmix1, sc1t, Wp1s, Wp1v, Wp10, Wp11,
                                      wrd1, out0, out1, d1);
    edge_mlp<<<EE / 64, 256, 0, stream>>>(out0, pos, shifts, eidx, elist, rowoff,
                                          Wr2a, Wr2b, msg, ue4);
    k_gather<<<NN / 4, 256, 0, stream>>>(rowoff, msg, ue4, A);
    node2<<<NBLK2, 512, 0, stream>>>(belem, bbase, blim, order, A, out1, d1,
                                     Wmix2, Wsc2, Wpr2, Wp2, Wv, Wg1, bg1,
                                     Wg2, bg2, wrd2, dip);
    k_total_part<<<NHB, 256, 0, stream>>>(dip, chg, pos, batch, wtotal);
    k_total_final<<<1, 96, 0, stream>>>(wtotal, total);
}